// Round 8
// baseline (1455.090 us; speedup 1.0000x reference)
//
#include <hip/hip_runtime.h>
#include <hip/hip_bf16.h>
#include <cstdint>

// Problem constants
#define BB 64
#define SS 1024
#define DCn 64
#define Hn 128
#define G3 384

using f32x4 = __attribute__((ext_vector_type(4))) float;
using bf16x8 = __attribute__((ext_vector_type(8))) short;

__device__ __forceinline__ float sigmoid_f(float x) {
  return 1.0f / (1.0f + __expf(-x));
}
__device__ __forceinline__ float tanh_f(float x) {
  float xc = fminf(fmaxf(x, -15.0f), 15.0f);
  float t = __expf(-2.0f * xc);
  return (1.0f - t) / (1.0f + t);
}
__device__ __forceinline__ short f2bf(float x) {
  union { float f; uint32_t u; } v; v.f = x;
  uint32_t r = v.u + 0x7FFFu + ((v.u >> 16) & 1u);   // RNE
  return (short)(r >> 16);
}
__device__ __forceinline__ f32x4 bf4f(ushort4 u) {
  union { uint32_t i; float f; } a, b, c, d;
  a.i = (uint32_t)u.x << 16; b.i = (uint32_t)u.y << 16;
  c.i = (uint32_t)u.z << 16; d.i = (uint32_t)u.w << 16;
  f32x4 r; r[0] = a.f; r[1] = b.f; r[2] = c.f; r[3] = d.f; return r;
}

// LDS-only barrier: does NOT drain vmcnt -> global loads/stores stay in
// flight across steps (the __syncthreads() vmcnt(0) drain was costing
// ~1700 cyc/step). Pattern verified by the 8-phase GEMM template (T3/T4).
#define LDS_BARRIER() do {                                   \
    asm volatile("s_waitcnt lgkmcnt(0)" ::: "memory");       \
    __builtin_amdgcn_s_barrier();                            \
    __builtin_amdgcn_sched_barrier(0);                       \
  } while (0)

// ---------------- Phase A: embeddings + conditional concat -> inter, concept
__global__ __launch_bounds__(256) void embed_kernel(
    const int* __restrict__ qseq, const int* __restrict__ cseq,
    const int* __restrict__ q2c, const int* __restrict__ q2cm,
    const float* __restrict__ cemb, const float* __restrict__ remb,
    float* __restrict__ inter, float* __restrict__ concept) {
  int pos = blockIdx.x * 2 + (threadIdx.x >> 7);   // [0, 65536)
  int d = threadIdx.x & 127;
  int q = qseq[pos];
  int corr = cseq[pos];
  float val;
  if (d < 64) {
    float acc = 0.f, msum = 0.f;
#pragma unroll
    for (int c = 0; c < 4; ++c) {
      int id = q2c[q * 4 + c];
      float m = (float)q2cm[q * 4 + c];
      acc += m * cemb[id * 64 + d];
      msum += m;
    }
    val = acc / fmaxf(msum, 1.0f);
    concept[(size_t)pos * 64 + d] = val;
  } else {
    val = remb[corr * 64 + (d - 64)];
  }
  // corr==1: [concept|corr]  else [corr|concept]
  int slot = (corr == 1) ? d : ((d < 64) ? d + 64 : d - 64);
  inter[(size_t)pos * 128 + slot] = val;
}

// ---------------- Generic f32 GEMM: C[M,N] = A[M,128] * Bm[N,128]^T + bias[N]
__global__ __launch_bounds__(256) void gemm_bt_kernel(
    const float* __restrict__ A, const float* __restrict__ Bm,
    const float* __restrict__ bias, float* __restrict__ C, int N) {
  __shared__ float4 As4[64][32];
  __shared__ float4 Bs4[64][32];
  const int m0 = blockIdx.x * 64;
  const int n0 = blockIdx.y * 64;
  const int tid = threadIdx.x;
  const float4* Ag = (const float4*)(A) + (size_t)m0 * 32;
  const float4* Bg = (const float4*)(Bm) + (size_t)n0 * 32;
#pragma unroll
  for (int l = 0; l < 8; ++l) {
    int idx = tid + l * 256;        // 0..2047
    int r = idx >> 5, k4 = idx & 31;
    int c = k4 ^ ((r >> 2) & 7);
    As4[r][c] = Ag[(size_t)r * 32 + k4];
    Bs4[r][c] = Bg[(size_t)r * 32 + k4];
  }
  __syncthreads();
  const int t16 = tid >> 4;  // 0..15 (row group)
  const int tn = tid & 15;   // 0..15 (col group)
  float acc[4][4] = {};
#pragma unroll
  for (int k4 = 0; k4 < 32; ++k4) {
    float4 a[4], b[4];
    int ca = k4 ^ (t16 & 7);
    int cb = k4 ^ (tn & 7);
#pragma unroll
    for (int i = 0; i < 4; ++i) a[i] = As4[t16 * 4 + i][ca];
#pragma unroll
    for (int j = 0; j < 4; ++j) b[j] = Bs4[tn * 4 + j][cb];
#pragma unroll
    for (int i = 0; i < 4; ++i)
#pragma unroll
      for (int j = 0; j < 4; ++j)
        acc[i][j] += a[i].x * b[j].x + a[i].y * b[j].y +
                     a[i].z * b[j].z + a[i].w * b[j].w;
  }
  float4 bv;
  bv.x = bias[n0 + tn * 4 + 0];
  bv.y = bias[n0 + tn * 4 + 1];
  bv.z = bias[n0 + tn * 4 + 2];
  bv.w = bias[n0 + tn * 4 + 3];
#pragma unroll
  for (int i = 0; i < 4; ++i) {
    float4 o;
    o.x = acc[i][0] + bv.x;
    o.y = acc[i][1] + bv.y;
    o.z = acc[i][2] + bv.z;
    o.w = acc[i][3] + bv.w;
    *(float4*)&C[(size_t)(m0 + t16 * 4 + i) * N + n0 + tn * 4] = o;
  }
}

// ---------------- Same GEMM but bf16 output (for Xp): halves write traffic
// and halves the GRU's streaming reads.
__global__ __launch_bounds__(256) void gemm_btb_kernel(
    const float* __restrict__ A, const float* __restrict__ Bm,
    const float* __restrict__ bias, ushort* __restrict__ C, int N) {
  __shared__ float4 As4[64][32];
  __shared__ float4 Bs4[64][32];
  const int m0 = blockIdx.x * 64;
  const int n0 = blockIdx.y * 64;
  const int tid = threadIdx.x;
  const float4* Ag = (const float4*)(A) + (size_t)m0 * 32;
  const float4* Bg = (const float4*)(Bm) + (size_t)n0 * 32;
#pragma unroll
  for (int l = 0; l < 8; ++l) {
    int idx = tid + l * 256;
    int r = idx >> 5, k4 = idx & 31;
    int c = k4 ^ ((r >> 2) & 7);
    As4[r][c] = Ag[(size_t)r * 32 + k4];
    Bs4[r][c] = Bg[(size_t)r * 32 + k4];
  }
  __syncthreads();
  const int t16 = tid >> 4;
  const int tn = tid & 15;
  float acc[4][4] = {};
#pragma unroll
  for (int k4 = 0; k4 < 32; ++k4) {
    float4 a[4], b[4];
    int ca = k4 ^ (t16 & 7);
    int cb = k4 ^ (tn & 7);
#pragma unroll
    for (int i = 0; i < 4; ++i) a[i] = As4[t16 * 4 + i][ca];
#pragma unroll
    for (int j = 0; j < 4; ++j) b[j] = Bs4[tn * 4 + j][cb];
#pragma unroll
    for (int i = 0; i < 4; ++i)
#pragma unroll
      for (int j = 0; j < 4; ++j)
        acc[i][j] += a[i].x * b[j].x + a[i].y * b[j].y +
                     a[i].z * b[j].z + a[i].w * b[j].w;
  }
  float4 bv;
  bv.x = bias[n0 + tn * 4 + 0];
  bv.y = bias[n0 + tn * 4 + 1];
  bv.z = bias[n0 + tn * 4 + 2];
  bv.w = bias[n0 + tn * 4 + 3];
#pragma unroll
  for (int i = 0; i < 4; ++i) {
    ushort4 o;
    o.x = (ushort)f2bf(acc[i][0] + bv.x);
    o.y = (ushort)f2bf(acc[i][1] + bv.y);
    o.z = (ushort)f2bf(acc[i][2] + bv.z);
    o.w = (ushort)f2bf(acc[i][3] + bv.w);
    *(ushort4*)&C[(size_t)(m0 + t16 * 4 + i) * N + n0 + tn * 4] = o;
  }
}

// ---------------- Phase C: MFMA GRU. 64 blocks x 1 batch, 512 threads.
// Per step: gh[384] = W_hh[384,128] x h[128] via mfma_f32_16x16x32_bf16 with
// all 16 B-cols carrying the SAME batch (wave-uniform addresses: LDS reads
// broadcast, Xp loads single-transaction). Wave w owns gate-rows
// {w*16(r), 128+w*16(z), 256+w*16(n)}; A and B use the SAME k-mapping
// (k = (lane>>4)*8 + j + 32*ks) so any HW k-permutation cancels.
// h double-buffered in LDS (bf16): ONE LDS-only barrier per step; global
// loads (depth-2 Xp prefetch) and rnn_out stores stay in flight across it.
__global__ __attribute__((amdgpu_flat_work_group_size(512, 512)))
__attribute__((amdgpu_waves_per_eu(2, 2))) void gru_kernel(
    const ushort* __restrict__ Xp, const float* __restrict__ W_hh,
    const float* __restrict__ b_hh, float* __restrict__ rnn_out) {
  const int tid = threadIdx.x;
  const int w = tid >> 6;          // wave 0..7 -> h-dims [w*16, w*16+16)
  const int lane = tid & 63;
  const int ln = lane & 15;        // W row within tile (batch col duplicated)
  const int c = lane >> 4;         // k-group 0..3
  const int b = blockIdx.x;        // one batch per block

  __shared__ alignas(16) short hlds[2][128];   // bf16 h, double-buffered

  // --- preload W_hh bf16 A-fragments: wf[gate][ksub], row = base + ln,
  //     k = ks*32 + c*8 + j  (same mapping as B-frag reads below)
  bf16x8 wf[3][4];
#pragma unroll
  for (int gt = 0; gt < 3; ++gt) {
    const float* wr = W_hh + (size_t)(gt * 128 + w * 16 + ln) * 128 + c * 8;
#pragma unroll
    for (int ks = 0; ks < 4; ++ks) {
      bf16x8 f;
#pragma unroll
      for (int j = 0; j < 8; ++j) f[j] = f2bf(wr[ks * 32 + j]);
      wf[gt][ks] = f;
    }
  }
  // --- per-reg biases (gate-dim rows w*16 + c*4 + reg)
  const f32x4 br = *(const f32x4*)(b_hh + w * 16 + c * 4);
  const f32x4 bz = *(const f32x4*)(b_hh + 128 + w * 16 + c * 4);
  const f32x4 bn = *(const f32x4*)(b_hh + 256 + w * 16 + c * 4);

  if (tid < 128) hlds[0][tid] = 0;             // h(-1) = 0

  const ushort* xb = Xp + (size_t)b * SS * G3 + w * 16 + c * 4;
  float* rb = rnn_out + (size_t)b * SS * Hn + w * 16 + c * 4;

  // depth-2 Xp prefetch (wave-uniform addresses -> broadcast loads)
  ushort4 xrA = *(const ushort4*)(xb + 0);
  ushort4 xzA = *(const ushort4*)(xb + 128);
  ushort4 xnA = *(const ushort4*)(xb + 256);
  ushort4 xrB = *(const ushort4*)(xb + G3 + 0);
  ushort4 xzB = *(const ushort4*)(xb + G3 + 128);
  ushort4 xnB = *(const ushort4*)(xb + G3 + 256);

  f32x4 h_old = {0.f, 0.f, 0.f, 0.f};
  LDS_BARRIER();

  for (int t = 0; t < SS; ++t) {
    // --- B-fragments of h from LDS buf[t&1] (broadcast, conflict-free)
    const short* hr = hlds[t & 1];
    bf16x8 h0 = *(const bf16x8*)(hr + 0 * 32 + c * 8);
    bf16x8 h1 = *(const bf16x8*)(hr + 1 * 32 + c * 8);
    bf16x8 h2 = *(const bf16x8*)(hr + 2 * 32 + c * 8);
    bf16x8 h3 = *(const bf16x8*)(hr + 3 * 32 + c * 8);
    // --- prefetch Xp(t+2) (stays in flight across the barrier)
    ushort4 xrC = {0, 0, 0, 0}, xzC = {0, 0, 0, 0}, xnC = {0, 0, 0, 0};
    if (t + 2 < SS) {
      const ushort* xp2 = xb + (size_t)(t + 2) * G3;
      xrC = *(const ushort4*)(xp2 + 0);
      xzC = *(const ushort4*)(xp2 + 128);
      xnC = *(const ushort4*)(xp2 + 256);
    }
    // keep W frags opaque/resident (loop-carried defs)
    asm volatile("" : "+v"(wf[0][0]), "+v"(wf[0][1]), "+v"(wf[0][2]), "+v"(wf[0][3]));
    asm volatile("" : "+v"(wf[1][0]), "+v"(wf[1][1]), "+v"(wf[1][2]), "+v"(wf[1][3]));
    asm volatile("" : "+v"(wf[2][0]), "+v"(wf[2][1]), "+v"(wf[2][2]), "+v"(wf[2][3]));
    // --- gh = W . h  (bias as C-in); 3 independent k-chains of 4
    f32x4 ar = br, az = bz, an = bn;
    ar = __builtin_amdgcn_mfma_f32_16x16x32_bf16(wf[0][0], h0, ar, 0, 0, 0);
    az = __builtin_amdgcn_mfma_f32_16x16x32_bf16(wf[1][0], h0, az, 0, 0, 0);
    an = __builtin_amdgcn_mfma_f32_16x16x32_bf16(wf[2][0], h0, an, 0, 0, 0);
    ar = __builtin_amdgcn_mfma_f32_16x16x32_bf16(wf[0][1], h1, ar, 0, 0, 0);
    az = __builtin_amdgcn_mfma_f32_16x16x32_bf16(wf[1][1], h1, az, 0, 0, 0);
    an = __builtin_amdgcn_mfma_f32_16x16x32_bf16(wf[2][1], h1, an, 0, 0, 0);
    ar = __builtin_amdgcn_mfma_f32_16x16x32_bf16(wf[0][2], h2, ar, 0, 0, 0);
    az = __builtin_amdgcn_mfma_f32_16x16x32_bf16(wf[1][2], h2, az, 0, 0, 0);
    an = __builtin_amdgcn_mfma_f32_16x16x32_bf16(wf[2][2], h2, an, 0, 0, 0);
    ar = __builtin_amdgcn_mfma_f32_16x16x32_bf16(wf[0][3], h3, ar, 0, 0, 0);
    az = __builtin_amdgcn_mfma_f32_16x16x32_bf16(wf[1][3], h3, az, 0, 0, 0);
    an = __builtin_amdgcn_mfma_f32_16x16x32_bf16(wf[2][3], h3, an, 0, 0, 0);
    // --- gates (all lanes compute duplicates; only ln==0 publishes)
    f32x4 xr = bf4f(xrA), xz = bf4f(xzA), xn = bf4f(xnA);
    f32x4 hn_v;
#pragma unroll
    for (int q = 0; q < 4; ++q) {
      float r = sigmoid_f(xr[q] + ar[q]);
      float z = sigmoid_f(xz[q] + az[q]);
      float a = xn[q] + r * an[q];
      float e = __expf(-2.0f * a);                       // tanh(a)=2/(1+e)-1
      float n = 2.0f * __builtin_amdgcn_rcpf(1.0f + e) - 1.0f;
      hn_v[q] = n + z * (h_old[q] - n);
    }
    h_old = hn_v;
    if (ln == 0) {
      union { short s[4]; uint2 u2; } pk;
#pragma unroll
      for (int q = 0; q < 4; ++q) pk.s[q] = f2bf(hn_v[q]);
      *(uint2*)(hlds[(t + 1) & 1] + w * 16 + c * 4) = pk.u2;   // h(t) -> other buf
    }
    LDS_BARRIER();               // LDS-visibility only; vmcnt NOT drained
    if (ln == 0)
      *(f32x4*)(rb + (size_t)t * Hn) = hn_v;   // off critical path, in-flight
    xrA = xrB; xzA = xzB; xnA = xnB;
    xrB = xrC; xzB = xzC; xnB = xnC;
  }
}

// ---------------- Phase D2: s[pos] = sum_a tanh(tmpA[pos,a]) * sim_w[a]
__global__ __launch_bounds__(256) void score_kernel(
    const float* __restrict__ tmpA, const float* __restrict__ sim_w,
    float* __restrict__ s) {
  int pos = blockIdx.x * 4 + (threadIdx.x >> 6);
  int lane = threadIdx.x & 63;
  const float* row = tmpA + (size_t)pos * 128;
  float v = tanh_f(row[lane]) * sim_w[lane] +
            tanh_f(row[lane + 64]) * sim_w[lane + 64];
#pragma unroll
  for (int o = 32; o; o >>= 1) v += __shfl_down(v, o);
  if (lane == 0) s[pos] = v;
}

// ---------------- Phase E: cumulative softmax-average + exclusive cumsum.
// 128 blocks (b x h-half) x 64 threads: halves per-CU BW vs 64-block version.
__global__ __launch_bounds__(64) void attn_kernel(
    const float* __restrict__ s, const float* __restrict__ rnn,
    float* __restrict__ excl) {
  const int b = blockIdx.x >> 1;
  const int h = ((blockIdx.x & 1) << 6) + threadIdx.x;
  const int tl = threadIdx.x;     // 0..63
  __shared__ float elds[SS];
  const float* sb = s + (size_t)b * SS;
  float m = -1e30f;
  for (int i = tl; i < SS; i += 64) m = fmaxf(m, sb[i]);
#pragma unroll
  for (int o = 32; o; o >>= 1) m = fmaxf(m, __shfl_xor(m, o));
  for (int i = tl; i < SS; i += 64) elds[i] = __expf(sb[i] - m);
  __syncthreads();

  const float* rb = rnn + (size_t)b * SS * Hn + h;
  float* eb = excl + (size_t)b * SS * Hn + h;
  float num = 0.f, den = 0.f, run = 0.f;
  float rcur = rb[0];
  for (int t = 0; t < SS; ++t) {
    float rnxt = (t < SS - 1) ? rb[(size_t)(t + 1) * Hn] : 0.0f;
    float e = elds[t];
    den += e;
    num += e * rcur;
    eb[(size_t)t * Hn] = run;                        // exclusive
    run += num * __builtin_amdgcn_rcpf(den);         // attn_t
    rcur = rnxt;
  }
}

// ---------------- Phase F: logits -> sigmoid. One wave per (b, t).
__global__ __launch_bounds__(256) void out_kernel(
    const float* __restrict__ excl, const float* __restrict__ rnn,
    const float* __restrict__ concept, const float* __restrict__ pred_w,
    const float* __restrict__ pred_b, float* __restrict__ out) {
  int idx = blockIdx.x * 4 + (threadIdx.x >> 6);    // [0, 64*1023)
  int lane = threadIdx.x & 63;
  if (idx >= BB * (SS - 1)) return;
  int b = idx / (SS - 1), t = idx % (SS - 1);
  const float* e = excl + ((size_t)b * SS + t) * Hn;
  const float* r = rnn + ((size_t)b * SS + t) * Hn;
  const float* c = concept + ((size_t)b * SS + t + 1) * DCn;
  float v = e[lane] * pred_w[lane] + e[lane + 64] * pred_w[lane + 64] +
            r[lane] * pred_w[128 + lane] + r[lane + 64] * pred_w[192 + lane] +
            c[lane] * pred_w[256 + lane];
#pragma unroll
  for (int o = 32; o; o >>= 1) v += __shfl_down(v, o);
  if (lane == 0) out[idx] = sigmoid_f(v + pred_b[0]);
}

extern "C" void kernel_launch(void* const* d_in, const int* in_sizes, int n_in,
                              void* d_out, int out_size, void* d_ws, size_t ws_size,
                              hipStream_t stream) {
  const int* qseq = (const int*)d_in[0];
  const int* cseq = (const int*)d_in[1];
  const int* q2c = (const int*)d_in[2];
  const int* q2cm = (const int*)d_in[3];
  const float* cemb = (const float*)d_in[4];
  const float* remb = (const float*)d_in[5];
  const float* mlp_w = (const float*)d_in[6];
  const float* mlp_b = (const float*)d_in[7];
  const float* sim_w = (const float*)d_in[8];
  const float* W_ih = (const float*)d_in[9];
  const float* b_ih = (const float*)d_in[10];
  const float* W_hh = (const float*)d_in[11];
  const float* b_hh = (const float*)d_in[12];
  const float* pred_w = (const float*)d_in[13];
  const float* pred_b = (const float*)d_in[14];
  float* out = (float*)d_out;

  // workspace layout (f32 elements)
  float* ws = (float*)d_ws;
  float* concept = ws;                 // [B,S,64] f32,  live A..F
  float* inter = ws + 4194304;         // [B,S,128] f32, live A..B1
  ushort* Xp = (ushort*)(ws + 12582912); // [B,S,384] bf16 (50MB), live B1..C
  float* rnn = ws + 37748736;          // [B,S,128] f32, live C..F
  float* tmpA = inter;                 // alias (inter dead after B1)
  float* excl = ws + 12582912;         // alias over dead Xp region (33MB)
  float* sbuf = ws + 20971520;         // alias, after excl, inside dead Xp

  embed_kernel<<<32768, 256, 0, stream>>>(qseq, cseq, q2c, q2cm, cemb, remb,
                                          inter, concept);
  gemm_btb_kernel<<<dim3(1024, 6), 256, 0, stream>>>(inter, W_ih, b_ih, Xp, 384);
  gru_kernel<<<64, 512, 0, stream>>>(Xp, W_hh, b_hh, rnn);
  gemm_bt_kernel<<<dim3(1024, 2), 256, 0, stream>>>(rnn, mlp_w, mlp_b, tmpA, 128);
  score_kernel<<<16384, 256, 0, stream>>>(tmpA, sim_w, sbuf);
  attn_kernel<<<128, 64, 0, stream>>>(sbuf, rnn, excl);
  out_kernel<<<16368, 256, 0, stream>>>(excl, rnn, concept, pred_w, pred_b, out);
}

// Round 9
// 980.528 us; speedup vs baseline: 1.4840x; 1.4840x over previous
//
#include <hip/hip_runtime.h>
#include <hip/hip_bf16.h>
#include <cstdint>

// Problem constants
#define BB 64
#define SS 1024
#define DCn 64
#define Hn 128
#define G3 384

using f32x4 = __attribute__((ext_vector_type(4))) float;
using bf16x8 = __attribute__((ext_vector_type(8))) short;

__device__ __forceinline__ float sigmoid_f(float x) {
  return 1.0f / (1.0f + __expf(-x));
}
__device__ __forceinline__ float tanh_f(float x) {
  float xc = fminf(fmaxf(x, -15.0f), 15.0f);
  float t = __expf(-2.0f * xc);
  return (1.0f - t) / (1.0f + t);
}
__device__ __forceinline__ short f2bf(float x) {
  union { float f; uint32_t u; } v; v.f = x;
  uint32_t r = v.u + 0x7FFFu + ((v.u >> 16) & 1u);   // RNE
  return (short)(r >> 16);
}
__device__ __forceinline__ float bf2f(ushort u) {
  union { uint32_t i; float f; } v; v.i = (uint32_t)u << 16; return v.f;
}
// compile-time-indexed 2-level select (no runtime array index -> no scratch)
__device__ __forceinline__ float sel4(f32x4 v, int q) {
  float t0 = (q & 1) ? v[1] : v[0];
  float t1 = (q & 1) ? v[3] : v[2];
  return (q & 2) ? t1 : t0;
}

// LDS-only barrier: does NOT drain vmcnt -> global loads/stores stay in
// flight across steps.
#define LDS_BARRIER() do {                                   \
    asm volatile("s_waitcnt lgkmcnt(0)" ::: "memory");       \
    __builtin_amdgcn_s_barrier();                            \
    __builtin_amdgcn_sched_barrier(0);                       \
  } while (0)

// ---------------- Phase A: embeddings + conditional concat -> inter, concept
__global__ __launch_bounds__(256) void embed_kernel(
    const int* __restrict__ qseq, const int* __restrict__ cseq,
    const int* __restrict__ q2c, const int* __restrict__ q2cm,
    const float* __restrict__ cemb, const float* __restrict__ remb,
    float* __restrict__ inter, float* __restrict__ concept) {
  int pos = blockIdx.x * 2 + (threadIdx.x >> 7);   // [0, 65536)
  int d = threadIdx.x & 127;
  int q = qseq[pos];
  int corr = cseq[pos];
  float val;
  if (d < 64) {
    float acc = 0.f, msum = 0.f;
#pragma unroll
    for (int c = 0; c < 4; ++c) {
      int id = q2c[q * 4 + c];
      float m = (float)q2cm[q * 4 + c];
      acc += m * cemb[id * 64 + d];
      msum += m;
    }
    val = acc / fmaxf(msum, 1.0f);
    concept[(size_t)pos * 64 + d] = val;
  } else {
    val = remb[corr * 64 + (d - 64)];
  }
  // corr==1: [concept|corr]  else [corr|concept]
  int slot = (corr == 1) ? d : ((d < 64) ? d + 64 : d - 64);
  inter[(size_t)pos * 128 + slot] = val;
}

// ---------------- Generic f32 GEMM: C[M,N] = A[M,128] * Bm[N,128]^T + bias[N]
__global__ __launch_bounds__(256) void gemm_bt_kernel(
    const float* __restrict__ A, const float* __restrict__ Bm,
    const float* __restrict__ bias, float* __restrict__ C, int N) {
  __shared__ float4 As4[64][32];
  __shared__ float4 Bs4[64][32];
  const int m0 = blockIdx.x * 64;
  const int n0 = blockIdx.y * 64;
  const int tid = threadIdx.x;
  const float4* Ag = (const float4*)(A) + (size_t)m0 * 32;
  const float4* Bg = (const float4*)(Bm) + (size_t)n0 * 32;
#pragma unroll
  for (int l = 0; l < 8; ++l) {
    int idx = tid + l * 256;        // 0..2047
    int r = idx >> 5, k4 = idx & 31;
    int c = k4 ^ ((r >> 2) & 7);
    As4[r][c] = Ag[(size_t)r * 32 + k4];
    Bs4[r][c] = Bg[(size_t)r * 32 + k4];
  }
  __syncthreads();
  const int t16 = tid >> 4;  // 0..15 (row group)
  const int tn = tid & 15;   // 0..15 (col group)
  float acc[4][4] = {};
#pragma unroll
  for (int k4 = 0; k4 < 32; ++k4) {
    float4 a[4], b[4];
    int ca = k4 ^ (t16 & 7);
    int cb = k4 ^ (tn & 7);
#pragma unroll
    for (int i = 0; i < 4; ++i) a[i] = As4[t16 * 4 + i][ca];
#pragma unroll
    for (int j = 0; j < 4; ++j) b[j] = Bs4[tn * 4 + j][cb];
#pragma unroll
    for (int i = 0; i < 4; ++i)
#pragma unroll
      for (int j = 0; j < 4; ++j)
        acc[i][j] += a[i].x * b[j].x + a[i].y * b[j].y +
                     a[i].z * b[j].z + a[i].w * b[j].w;
  }
  float4 bv;
  bv.x = bias[n0 + tn * 4 + 0];
  bv.y = bias[n0 + tn * 4 + 1];
  bv.z = bias[n0 + tn * 4 + 2];
  bv.w = bias[n0 + tn * 4 + 3];
#pragma unroll
  for (int i = 0; i < 4; ++i) {
    float4 o;
    o.x = acc[i][0] + bv.x;
    o.y = acc[i][1] + bv.y;
    o.z = acc[i][2] + bv.z;
    o.w = acc[i][3] + bv.w;
    *(float4*)&C[(size_t)(m0 + t16 * 4 + i) * N + n0 + tn * 4] = o;
  }
}

// ---------------- Same GEMM but bf16 output (for Xp): halves write traffic
// and halves the GRU's streaming reads.
__global__ __launch_bounds__(256) void gemm_btb_kernel(
    const float* __restrict__ A, const float* __restrict__ Bm,
    const float* __restrict__ bias, ushort* __restrict__ C, int N) {
  __shared__ float4 As4[64][32];
  __shared__ float4 Bs4[64][32];
  const int m0 = blockIdx.x * 64;
  const int n0 = blockIdx.y * 64;
  const int tid = threadIdx.x;
  const float4* Ag = (const float4*)(A) + (size_t)m0 * 32;
  const float4* Bg = (const float4*)(Bm) + (size_t)n0 * 32;
#pragma unroll
  for (int l = 0; l < 8; ++l) {
    int idx = tid + l * 256;
    int r = idx >> 5, k4 = idx & 31;
    int c = k4 ^ ((r >> 2) & 7);
    As4[r][c] = Ag[(size_t)r * 32 + k4];
    Bs4[r][c] = Bg[(size_t)r * 32 + k4];
  }
  __syncthreads();
  const int t16 = tid >> 4;
  const int tn = tid & 15;
  float acc[4][4] = {};
#pragma unroll
  for (int k4 = 0; k4 < 32; ++k4) {
    float4 a[4], b[4];
    int ca = k4 ^ (t16 & 7);
    int cb = k4 ^ (tn & 7);
#pragma unroll
    for (int i = 0; i < 4; ++i) a[i] = As4[t16 * 4 + i][ca];
#pragma unroll
    for (int j = 0; j < 4; ++j) b[j] = Bs4[tn * 4 + j][cb];
#pragma unroll
    for (int i = 0; i < 4; ++i)
#pragma unroll
      for (int j = 0; j < 4; ++j)
        acc[i][j] += a[i].x * b[j].x + a[i].y * b[j].y +
                     a[i].z * b[j].z + a[i].w * b[j].w;
  }
  float4 bv;
  bv.x = bias[n0 + tn * 4 + 0];
  bv.y = bias[n0 + tn * 4 + 1];
  bv.z = bias[n0 + tn * 4 + 2];
  bv.w = bias[n0 + tn * 4 + 3];
#pragma unroll
  for (int i = 0; i < 4; ++i) {
    ushort4 o;
    o.x = (ushort)f2bf(acc[i][0] + bv.x);
    o.y = (ushort)f2bf(acc[i][1] + bv.y);
    o.z = (ushort)f2bf(acc[i][2] + bv.z);
    o.w = (ushort)f2bf(acc[i][3] + bv.w);
    *(ushort4*)&C[(size_t)(m0 + t16 * 4 + i) * N + n0 + tn * 4] = o;
  }
}

// ---------------- Phase C: MFMA GRU. 64 blocks x 1 batch, 512 threads.
// gh[384] = W_hh x h via 12x mfma_f32_16x16x32_bf16 (cols duplicate the one
// batch). Wave w owns gate-rows {w*16(r), +128(z), +256(n)}; A and B use the
// SAME k-mapping so HW k-permutation cancels. Post-MFMA gate math is
// q-SELECTED: lane (c,ln) computes only q=ln&3 via cndmask selects (6 trans
// + ~25 VALU vs 24 trans + ~84 VALU for all-q) -- the kernel was VALU-issue
// bound (per-active-CU VALUBusy ~70%). No asm pins: wf feeds MFMAs directly
// (AGPR-native); pins forced per-step accvgpr copy storms.
__global__ __attribute__((amdgpu_flat_work_group_size(512, 512)))
__attribute__((amdgpu_waves_per_eu(2, 2))) void gru_kernel(
    const ushort* __restrict__ Xp, const float* __restrict__ W_hh,
    const float* __restrict__ b_hh, float* __restrict__ rnn_out) {
  const int tid = threadIdx.x;
  const int w = tid >> 6;          // wave 0..7 -> h-dims [w*16, w*16+16)
  const int lane = tid & 63;
  const int ln = lane & 15;        // W row within tile / duplicate batch col
  const int c = lane >> 4;         // k-group & row-quad 0..3
  const int qs = ln & 3;           // this lane's selected q
  const int b = blockIdx.x;        // one batch per block

  __shared__ alignas(16) short hlds[2][128];   // bf16 h, double-buffered

  // --- preload W_hh bf16 A-fragments: wf[gate][ksub], row = base + ln,
  //     k = ks*32 + c*8 + j  (same mapping as B-frag reads below)
  bf16x8 wf[3][4];
#pragma unroll
  for (int gt = 0; gt < 3; ++gt) {
    const float* wr = W_hh + (size_t)(gt * 128 + w * 16 + ln) * 128 + c * 8;
#pragma unroll
    for (int ks = 0; ks < 4; ++ks) {
      bf16x8 f;
#pragma unroll
      for (int j = 0; j < 8; ++j) f[j] = f2bf(wr[ks * 32 + j]);
      wf[gt][ks] = f;
    }
  }
  // --- per-reg biases (gate-dim rows w*16 + c*4 + reg)
  const f32x4 br = *(const f32x4*)(b_hh + w * 16 + c * 4);
  const f32x4 bz = *(const f32x4*)(b_hh + 128 + w * 16 + c * 4);
  const f32x4 bn = *(const f32x4*)(b_hh + 256 + w * 16 + c * 4);

  if (tid < 128) hlds[0][tid] = 0;             // h(-1) = 0

  const int dim = w * 16 + c * 4 + qs;         // this lane's h-dim
  const ushort* xs = Xp + (size_t)b * SS * G3 + dim;
  float* rs = rnn_out + (size_t)b * SS * Hn + w * 16 + c * 4 + ln; // ln<4 only

  // scalar depth-2 Xp prefetch (2B/lane x3)
  ushort xr0 = xs[0], xz0 = xs[128], xn0 = xs[256];
  ushort xr1 = xs[G3 + 0], xz1 = xs[G3 + 128], xn1 = xs[G3 + 256];

  float h_old = 0.0f;
  LDS_BARRIER();

  for (int t = 0; t < SS; ++t) {
    // --- B-fragments of h from LDS buf[t&1] (broadcast, conflict-free)
    const short* hr = hlds[t & 1];
    bf16x8 h0 = *(const bf16x8*)(hr + 0 * 32 + c * 8);
    bf16x8 h1 = *(const bf16x8*)(hr + 1 * 32 + c * 8);
    bf16x8 h2 = *(const bf16x8*)(hr + 2 * 32 + c * 8);
    bf16x8 h3 = *(const bf16x8*)(hr + 3 * 32 + c * 8);
    // --- prefetch Xp(t+2), stays in flight across the barrier
    ushort xr2 = 0, xz2 = 0, xn2 = 0;
    if (t + 2 < SS) {
      const ushort* x2 = xs + (size_t)(t + 2) * G3;
      xr2 = x2[0]; xz2 = x2[128]; xn2 = x2[256];
    }
    // --- gh = W . h  (bias as C-in); 3 independent k-chains of 4
    f32x4 ar = br, az = bz, an = bn;
    ar = __builtin_amdgcn_mfma_f32_16x16x32_bf16(wf[0][0], h0, ar, 0, 0, 0);
    az = __builtin_amdgcn_mfma_f32_16x16x32_bf16(wf[1][0], h0, az, 0, 0, 0);
    an = __builtin_amdgcn_mfma_f32_16x16x32_bf16(wf[2][0], h0, an, 0, 0, 0);
    ar = __builtin_amdgcn_mfma_f32_16x16x32_bf16(wf[0][1], h1, ar, 0, 0, 0);
    az = __builtin_amdgcn_mfma_f32_16x16x32_bf16(wf[1][1], h1, az, 0, 0, 0);
    an = __builtin_amdgcn_mfma_f32_16x16x32_bf16(wf[2][1], h1, an, 0, 0, 0);
    ar = __builtin_amdgcn_mfma_f32_16x16x32_bf16(wf[0][2], h2, ar, 0, 0, 0);
    az = __builtin_amdgcn_mfma_f32_16x16x32_bf16(wf[1][2], h2, az, 0, 0, 0);
    an = __builtin_amdgcn_mfma_f32_16x16x32_bf16(wf[2][2], h2, an, 0, 0, 0);
    ar = __builtin_amdgcn_mfma_f32_16x16x32_bf16(wf[0][3], h3, ar, 0, 0, 0);
    az = __builtin_amdgcn_mfma_f32_16x16x32_bf16(wf[1][3], h3, az, 0, 0, 0);
    an = __builtin_amdgcn_mfma_f32_16x16x32_bf16(wf[2][3], h3, an, 0, 0, 0);
    // --- q-selected scalar gates (each lane: only q = ln&3)
    float ga = sel4(ar, qs), gz = sel4(az, qs), gn = sel4(an, qs);
    float r = sigmoid_f(bf2f(xr0) + ga);
    float z = sigmoid_f(bf2f(xz0) + gz);
    float a = bf2f(xn0) + r * gn;
    float e = __expf(-2.0f * a);                       // tanh(a)=2/(1+e)-1
    float n = 2.0f * __builtin_amdgcn_rcpf(1.0f + e) - 1.0f;
    float hn = n + z * (h_old - n);
    h_old = hn;
    if (ln < 4)                                         // one publisher per dim
      hlds[(t + 1) & 1][w * 16 + c * 4 + ln] = f2bf(hn);
    LDS_BARRIER();               // LDS-visibility only; vmcnt NOT drained
    if (ln < 4)
      rs[(size_t)t * Hn] = hn;   // coalesced 64B/wave, off critical path
    xr0 = xr1; xz0 = xz1; xn0 = xn1;
    xr1 = xr2; xz1 = xz2; xn1 = xn2;
  }
}

// ---------------- Phase D2: s[pos] = sum_a tanh(tmpA[pos,a]) * sim_w[a]
__global__ __launch_bounds__(256) void score_kernel(
    const float* __restrict__ tmpA, const float* __restrict__ sim_w,
    float* __restrict__ s) {
  int pos = blockIdx.x * 4 + (threadIdx.x >> 6);
  int lane = threadIdx.x & 63;
  const float* row = tmpA + (size_t)pos * 128;
  float v = tanh_f(row[lane]) * sim_w[lane] +
            tanh_f(row[lane + 64]) * sim_w[lane + 64];
#pragma unroll
  for (int o = 32; o; o >>= 1) v += __shfl_down(v, o);
  if (lane == 0) s[pos] = v;
}

// ---------------- Phase E: cumulative softmax-average + exclusive cumsum.
// 128 blocks (b x h-half) x 64 threads.
__global__ __launch_bounds__(64) void attn_kernel(
    const float* __restrict__ s, const float* __restrict__ rnn,
    float* __restrict__ excl) {
  const int b = blockIdx.x >> 1;
  const int h = ((blockIdx.x & 1) << 6) + threadIdx.x;
  const int tl = threadIdx.x;     // 0..63
  __shared__ float elds[SS];
  const float* sb = s + (size_t)b * SS;
  float m = -1e30f;
  for (int i = tl; i < SS; i += 64) m = fmaxf(m, sb[i]);
#pragma unroll
  for (int o = 32; o; o >>= 1) m = fmaxf(m, __shfl_xor(m, o));
  for (int i = tl; i < SS; i += 64) elds[i] = __expf(sb[i] - m);
  __syncthreads();

  const float* rb = rnn + (size_t)b * SS * Hn + h;
  float* eb = excl + (size_t)b * SS * Hn + h;
  float num = 0.f, den = 0.f, run = 0.f;
  float rcur = rb[0];
  for (int t = 0; t < SS; ++t) {
    float rnxt = (t < SS - 1) ? rb[(size_t)(t + 1) * Hn] : 0.0f;
    float e = elds[t];
    den += e;
    num += e * rcur;
    eb[(size_t)t * Hn] = run;                        // exclusive
    run += num * __builtin_amdgcn_rcpf(den);         // attn_t
    rcur = rnxt;
  }
}

// ---------------- Phase F: logits -> sigmoid. One wave per (b, t).
__global__ __launch_bounds__(256) void out_kernel(
    const float* __restrict__ excl, const float* __restrict__ rnn,
    const float* __restrict__ concept, const float* __restrict__ pred_w,
    const float* __restrict__ pred_b, float* __restrict__ out) {
  int idx = blockIdx.x * 4 + (threadIdx.x >> 6);    // [0, 64*1023)
  int lane = threadIdx.x & 63;
  if (idx >= BB * (SS - 1)) return;
  int b = idx / (SS - 1), t = idx % (SS - 1);
  const float* e = excl + ((size_t)b * SS + t) * Hn;
  const float* r = rnn + ((size_t)b * SS + t) * Hn;
  const float* c = concept + ((size_t)b * SS + t + 1) * DCn;
  float v = e[lane] * pred_w[lane] + e[lane + 64] * pred_w[lane + 64] +
            r[lane] * pred_w[128 + lane] + r[lane + 64] * pred_w[192 + lane] +
            c[lane] * pred_w[256 + lane];
#pragma unroll
  for (int o = 32; o; o >>= 1) v += __shfl_down(v, o);
  if (lane == 0) out[idx] = sigmoid_f(v + pred_b[0]);
}

extern "C" void kernel_launch(void* const* d_in, const int* in_sizes, int n_in,
                              void* d_out, int out_size, void* d_ws, size_t ws_size,
                              hipStream_t stream) {
  const int* qseq = (const int*)d_in[0];
  const int* cseq = (const int*)d_in[1];
  const int* q2c = (const int*)d_in[2];
  const int* q2cm = (const int*)d_in[3];
  const float* cemb = (const float*)d_in[4];
  const float* remb = (const float*)d_in[5];
  const float* mlp_w = (const float*)d_in[6];
  const float* mlp_b = (const float*)d_in[7];
  const float* sim_w = (const float*)d_in[8];
  const float* W_ih = (const float*)d_in[9];
  const float* b_ih = (const float*)d_in[10];
  const float* W_hh = (const float*)d_in[11];
  const float* b_hh = (const float*)d_in[12];
  const float* pred_w = (const float*)d_in[13];
  const float* pred_b = (const float*)d_in[14];
  float* out = (float*)d_out;

  // workspace layout (f32 elements)
  float* ws = (float*)d_ws;
  float* concept = ws;                 // [B,S,64] f32,  live A..F
  float* inter = ws + 4194304;         // [B,S,128] f32, live A..B1
  ushort* Xp = (ushort*)(ws + 12582912); // [B,S,384] bf16 (50MB), live B1..C
  float* rnn = ws + 37748736;          // [B,S,128] f32, live C..F
  float* tmpA = inter;                 // alias (inter dead after B1)
  float* excl = ws + 12582912;         // alias over dead Xp region (33MB)
  float* sbuf = ws + 20971520;         // alias, after excl, inside dead Xp

  embed_kernel<<<32768, 256, 0, stream>>>(qseq, cseq, q2c, q2cm, cemb, remb,
                                          inter, concept);
  gemm_btb_kernel<<<dim3(1024, 6), 256, 0, stream>>>(inter, W_ih, b_ih, Xp, 384);
  gru_kernel<<<64, 512, 0, stream>>>(Xp, W_hh, b_hh, rnn);
  gemm_bt_kernel<<<dim3(1024, 2), 256, 0, stream>>>(rnn, mlp_w, mlp_b, tmpA, 128);
  score_kernel<<<16384, 256, 0, stream>>>(tmpA, sim_w, sbuf);
  attn_kernel<<<128, 64, 0, stream>>>(sbuf, rnn, excl);
  out_kernel<<<16368, 256, 0, stream>>>(excl, rnn, concept, pred_w, pred_b, out);
}

// Round 10
// 757.119 us; speedup vs baseline: 1.9219x; 1.2951x over previous
//
#include <hip/hip_runtime.h>
#include <hip/hip_bf16.h>
#include <cstdint>

// Problem constants
#define BB 64
#define SS 1024
#define DCn 64
#define Hn 128
#define G3 384

using f32x4 = __attribute__((ext_vector_type(4))) float;
using bf16x8 = __attribute__((ext_vector_type(8))) short;

__device__ __forceinline__ float sigmoid_f(float x) {
  return 1.0f / (1.0f + __expf(-x));
}
__device__ __forceinline__ float tanh_f(float x) {
  float xc = fminf(fmaxf(x, -15.0f), 15.0f);
  float t = __expf(-2.0f * xc);
  return (1.0f - t) / (1.0f + t);
}
__device__ __forceinline__ short f2bf(float x) {
  union { float f; uint32_t u; } v; v.f = x;
  uint32_t r = v.u + 0x7FFFu + ((v.u >> 16) & 1u);   // RNE
  return (short)(r >> 16);
}
__device__ __forceinline__ float bf2f(ushort u) {
  union { uint32_t i; float f; } v; v.i = (uint32_t)u << 16; return v.f;
}
// compile-time-indexed 2-level select (no runtime array index -> no scratch)
__device__ __forceinline__ float sel4(f32x4 v, int q) {
  float t0 = (q & 1) ? v[1] : v[0];
  float t1 = (q & 1) ? v[3] : v[2];
  return (q & 2) ? t1 : t0;
}

// LDS-only barrier: does NOT drain vmcnt -> global loads/stores stay in
// flight across steps.
#define LDS_BARRIER() do {                                   \
    asm volatile("s_waitcnt lgkmcnt(0)" ::: "memory");       \
    __builtin_amdgcn_s_barrier();                            \
    __builtin_amdgcn_sched_barrier(0);                       \
  } while (0)

// ---------------- weight conversion: W_ih, mlp_w -> bf16 (once per call)
__global__ __launch_bounds__(256) void convw_kernel(
    const float* __restrict__ W_ih, const float* __restrict__ mlp_w,
    ushort* __restrict__ Wihb, ushort* __restrict__ mlpwb) {
  int i = blockIdx.x * 256 + threadIdx.x;      // [0, 65536)
  if (i < 49152) Wihb[i] = (ushort)f2bf(W_ih[i]);
  else mlpwb[i - 49152] = (ushort)f2bf(mlp_w[i - 49152]);
}

// ---------------- Phase A: embeddings + conditional concat -> inter(bf16), concept(f32)
__global__ __launch_bounds__(256) void embed_kernel(
    const int* __restrict__ qseq, const int* __restrict__ cseq,
    const int* __restrict__ q2c, const int* __restrict__ q2cm,
    const float* __restrict__ cemb, const float* __restrict__ remb,
    ushort* __restrict__ interb, float* __restrict__ concept) {
  int pos = blockIdx.x * 2 + (threadIdx.x >> 7);   // [0, 65536)
  int d = threadIdx.x & 127;
  int q = qseq[pos];
  int corr = cseq[pos];
  float val;
  if (d < 64) {
    float acc = 0.f, msum = 0.f;
#pragma unroll
    for (int c = 0; c < 4; ++c) {
      int id = q2c[q * 4 + c];
      float m = (float)q2cm[q * 4 + c];
      acc += m * cemb[id * 64 + d];
      msum += m;
    }
    val = acc / fmaxf(msum, 1.0f);
    concept[(size_t)pos * 64 + d] = val;
  } else {
    val = remb[corr * 64 + (d - 64)];
  }
  // corr==1: [concept|corr]  else [corr|concept]
  int slot = (corr == 1) ? d : ((d < 64) ? d + 64 : d - 64);
  interb[(size_t)pos * 128 + slot] = (ushort)f2bf(val);
}

// ---------------- MFMA GEMM: C[M,N] = A[M,128] * Bm[N,128]^T + bias[N]
// 64x64 tile, K=128 one-shot, 256 threads (4 waves, wave w = N-cols w*16..+16).
// Same-k-mapping A/B fragments (k = ks*32 + c*8 + j) as the verified GRU, so
// any HW k-permutation cancels. LDS chunks XOR-swizzled by (row&15):
// frag reads hit 16 distinct rows x distinct chunk -> conflict-free.
template <bool AF32, bool OUTBF>
__global__ __launch_bounds__(256) void gemm_mfma_kernel(
    const void* __restrict__ Ap, const ushort* __restrict__ Bp,
    const float* __restrict__ bias, void* __restrict__ Cp, int N) {
  __shared__ bf16x8 Al[64][16];
  __shared__ bf16x8 Bl[64][16];
  const int m0 = blockIdx.x * 64, n0 = blockIdx.y * 64;
  const int tid = threadIdx.x;
  const int row = tid >> 2, j0 = (tid & 3) * 4;
  // stage A tile (convert f32->bf16 in flight if needed)
  if (AF32) {
    const float* A = (const float*)Ap + (size_t)(m0 + row) * 128 + j0 * 8;
#pragma unroll
    for (int jj = 0; jj < 4; ++jj) {
      f32x4 lo = *(const f32x4*)(A + jj * 8);
      f32x4 hi = *(const f32x4*)(A + jj * 8 + 4);
      bf16x8 v;
#pragma unroll
      for (int q = 0; q < 4; ++q) { v[q] = f2bf(lo[q]); v[4 + q] = f2bf(hi[q]); }
      Al[row][(j0 + jj) ^ (row & 15)] = v;
    }
  } else {
    const bf16x8* A = (const bf16x8*)Ap + (size_t)(m0 + row) * 16 + j0;
#pragma unroll
    for (int jj = 0; jj < 4; ++jj) Al[row][(j0 + jj) ^ (row & 15)] = A[jj];
  }
  // stage B tile (bf16 weights)
  {
    const bf16x8* Bg = (const bf16x8*)Bp + (size_t)(n0 + row) * 16 + j0;
#pragma unroll
    for (int jj = 0; jj < 4; ++jj) Bl[row][(j0 + jj) ^ (row & 15)] = Bg[jj];
  }
  __syncthreads();
  const int w = tid >> 6, lane = tid & 63, ln = lane & 15, cc = lane >> 4;
  bf16x8 bf[4];
#pragma unroll
  for (int ks = 0; ks < 4; ++ks) bf[ks] = Bl[w * 16 + ln][(ks * 4 + cc) ^ ln];
  f32x4 C0 = {0,0,0,0}, C1 = {0,0,0,0}, C2 = {0,0,0,0}, C3 = {0,0,0,0};
#pragma unroll
  for (int ks = 0; ks < 4; ++ks) {
    bf16x8 a0 = Al[0 * 16 + ln][(ks * 4 + cc) ^ ln];
    bf16x8 a1 = Al[1 * 16 + ln][(ks * 4 + cc) ^ ln];
    bf16x8 a2 = Al[2 * 16 + ln][(ks * 4 + cc) ^ ln];
    bf16x8 a3 = Al[3 * 16 + ln][(ks * 4 + cc) ^ ln];
    C0 = __builtin_amdgcn_mfma_f32_16x16x32_bf16(a0, bf[ks], C0, 0, 0, 0);
    C1 = __builtin_amdgcn_mfma_f32_16x16x32_bf16(a1, bf[ks], C1, 0, 0, 0);
    C2 = __builtin_amdgcn_mfma_f32_16x16x32_bf16(a2, bf[ks], C2, 0, 0, 0);
    C3 = __builtin_amdgcn_mfma_f32_16x16x32_bf16(a3, bf[ks], C3, 0, 0, 0);
  }
  const float bv = bias[n0 + w * 16 + ln];
  const size_t ncol = n0 + w * 16 + ln;
#pragma unroll
  for (int rt = 0; rt < 4; ++rt) {
    f32x4 Cf = (rt == 0) ? C0 : (rt == 1) ? C1 : (rt == 2) ? C2 : C3;
#pragma unroll
    for (int q = 0; q < 4; ++q) {
      float v = Cf[q] + bv;
      size_t idx = (size_t)(m0 + rt * 16 + cc * 4 + q) * N + ncol;
      if (OUTBF) ((ushort*)Cp)[idx] = (ushort)f2bf(v);
      else ((float*)Cp)[idx] = v;
    }
  }
}

// ---------------- Phase C: MFMA GRU. 64 blocks x 1 batch, 512 threads.
// (structure verified R6-R9; see R9 comments)
__global__ __attribute__((amdgpu_flat_work_group_size(512, 512)))
__attribute__((amdgpu_waves_per_eu(2, 2))) void gru_kernel(
    const ushort* __restrict__ Xp, const float* __restrict__ W_hh,
    const float* __restrict__ b_hh, float* __restrict__ rnn_out) {
  const int tid = threadIdx.x;
  const int w = tid >> 6;          // wave 0..7 -> h-dims [w*16, w*16+16)
  const int lane = tid & 63;
  const int ln = lane & 15;        // W row within tile / duplicate batch col
  const int c = lane >> 4;         // k-group & row-quad 0..3
  const int qs = ln & 3;           // this lane's selected q
  const int b = blockIdx.x;        // one batch per block

  __shared__ alignas(16) short hlds[2][128];   // bf16 h, double-buffered

  bf16x8 wf[3][4];
#pragma unroll
  for (int gt = 0; gt < 3; ++gt) {
    const float* wr = W_hh + (size_t)(gt * 128 + w * 16 + ln) * 128 + c * 8;
#pragma unroll
    for (int ks = 0; ks < 4; ++ks) {
      bf16x8 f;
#pragma unroll
      for (int j = 0; j < 8; ++j) f[j] = f2bf(wr[ks * 32 + j]);
      wf[gt][ks] = f;
    }
  }
  const f32x4 br = *(const f32x4*)(b_hh + w * 16 + c * 4);
  const f32x4 bz = *(const f32x4*)(b_hh + 128 + w * 16 + c * 4);
  const f32x4 bn = *(const f32x4*)(b_hh + 256 + w * 16 + c * 4);

  if (tid < 128) hlds[0][tid] = 0;             // h(-1) = 0

  const int dim = w * 16 + c * 4 + qs;         // this lane's h-dim
  const ushort* xs = Xp + (size_t)b * SS * G3 + dim;
  float* rs = rnn_out + (size_t)b * SS * Hn + w * 16 + c * 4 + ln; // ln<4 only

  ushort xr0 = xs[0], xz0 = xs[128], xn0 = xs[256];
  ushort xr1 = xs[G3 + 0], xz1 = xs[G3 + 128], xn1 = xs[G3 + 256];

  float h_old = 0.0f;
  LDS_BARRIER();

  for (int t = 0; t < SS; ++t) {
    const short* hr = hlds[t & 1];
    bf16x8 h0 = *(const bf16x8*)(hr + 0 * 32 + c * 8);
    bf16x8 h1 = *(const bf16x8*)(hr + 1 * 32 + c * 8);
    bf16x8 h2 = *(const bf16x8*)(hr + 2 * 32 + c * 8);
    bf16x8 h3 = *(const bf16x8*)(hr + 3 * 32 + c * 8);
    // branch-free prefetch Xp(t+2): last-batch overrun lands in the (allocated)
    // rnn region of d_ws -- garbage values, never consumed (shift regs drained)
    const ushort* x2 = xs + (size_t)(t + 2) * G3;
    ushort xr2 = x2[0], xz2 = x2[128], xn2 = x2[256];
    __builtin_amdgcn_s_setprio(1);
    f32x4 ar = br, az = bz, an = bn;
    ar = __builtin_amdgcn_mfma_f32_16x16x32_bf16(wf[0][0], h0, ar, 0, 0, 0);
    az = __builtin_amdgcn_mfma_f32_16x16x32_bf16(wf[1][0], h0, az, 0, 0, 0);
    an = __builtin_amdgcn_mfma_f32_16x16x32_bf16(wf[2][0], h0, an, 0, 0, 0);
    ar = __builtin_amdgcn_mfma_f32_16x16x32_bf16(wf[0][1], h1, ar, 0, 0, 0);
    az = __builtin_amdgcn_mfma_f32_16x16x32_bf16(wf[1][1], h1, az, 0, 0, 0);
    an = __builtin_amdgcn_mfma_f32_16x16x32_bf16(wf[2][1], h1, an, 0, 0, 0);
    ar = __builtin_amdgcn_mfma_f32_16x16x32_bf16(wf[0][2], h2, ar, 0, 0, 0);
    az = __builtin_amdgcn_mfma_f32_16x16x32_bf16(wf[1][2], h2, az, 0, 0, 0);
    an = __builtin_amdgcn_mfma_f32_16x16x32_bf16(wf[2][2], h2, an, 0, 0, 0);
    ar = __builtin_amdgcn_mfma_f32_16x16x32_bf16(wf[0][3], h3, ar, 0, 0, 0);
    az = __builtin_amdgcn_mfma_f32_16x16x32_bf16(wf[1][3], h3, az, 0, 0, 0);
    an = __builtin_amdgcn_mfma_f32_16x16x32_bf16(wf[2][3], h3, an, 0, 0, 0);
    __builtin_amdgcn_s_setprio(0);
    // q-selected scalar gates (each lane: only q = ln&3)
    float ga = sel4(ar, qs), gz = sel4(az, qs), gn = sel4(an, qs);
    float r = sigmoid_f(bf2f(xr0) + ga);
    float z = sigmoid_f(bf2f(xz0) + gz);
    float a = bf2f(xn0) + r * gn;
    float e = __expf(-2.0f * a);                       // tanh(a)=2/(1+e)-1
    float n = 2.0f * __builtin_amdgcn_rcpf(1.0f + e) - 1.0f;
    float hn = n + z * (h_old - n);
    h_old = hn;
    if (ln < 4)                                         // one publisher per dim
      hlds[(t + 1) & 1][w * 16 + c * 4 + ln] = f2bf(hn);
    LDS_BARRIER();               // LDS-visibility only; vmcnt NOT drained
    if (ln < 4)
      rs[(size_t)t * Hn] = hn;   // coalesced 64B/wave, off critical path
    xr0 = xr1; xz0 = xz1; xn0 = xn1;
    xr1 = xr2; xz1 = xz2; xn1 = xn2;
  }
}

// ---------------- Phase D2: s[pos] = sum_a tanh(tmpA[pos,a]) * sim_w[a]
__global__ __launch_bounds__(256) void score_kernel(
    const float* __restrict__ tmpA, const float* __restrict__ sim_w,
    float* __restrict__ s) {
  int pos = blockIdx.x * 4 + (threadIdx.x >> 6);
  int lane = threadIdx.x & 63;
  const float* row = tmpA + (size_t)pos * 128;
  float v = tanh_f(row[lane]) * sim_w[lane] +
            tanh_f(row[lane + 64]) * sim_w[lane + 64];
#pragma unroll
  for (int o = 32; o; o >>= 1) v += __shfl_down(v, o);
  if (lane == 0) s[pos] = v;
}

// ---------------- Phase E: cumulative softmax-average + exclusive cumsum.
// 128 blocks (b x h-half) x 64 threads.
__global__ __launch_bounds__(64) void attn_kernel(
    const float* __restrict__ s, const float* __restrict__ rnn,
    float* __restrict__ excl) {
  const int b = blockIdx.x >> 1;
  const int h = ((blockIdx.x & 1) << 6) + threadIdx.x;
  const int tl = threadIdx.x;     // 0..63
  __shared__ float elds[SS];
  const float* sb = s + (size_t)b * SS;
  float m = -1e30f;
  for (int i = tl; i < SS; i += 64) m = fmaxf(m, sb[i]);
#pragma unroll
  for (int o = 32; o; o >>= 1) m = fmaxf(m, __shfl_xor(m, o));
  for (int i = tl; i < SS; i += 64) elds[i] = __expf(sb[i] - m);
  __syncthreads();

  const float* rb = rnn + (size_t)b * SS * Hn + h;
  float* eb = excl + (size_t)b * SS * Hn + h;
  float num = 0.f, den = 0.f, run = 0.f;
  float rcur = rb[0];
  for (int t = 0; t < SS; ++t) {
    float rnxt = (t < SS - 1) ? rb[(size_t)(t + 1) * Hn] : 0.0f;
    float e = elds[t];
    den += e;
    num += e * rcur;
    eb[(size_t)t * Hn] = run;                        // exclusive
    run += num * __builtin_amdgcn_rcpf(den);         // attn_t
    rcur = rnxt;
  }
}

// ---------------- Phase F: logits -> sigmoid. One wave per (b, t).
__global__ __launch_bounds__(256) void out_kernel(
    const float* __restrict__ excl, const float* __restrict__ rnn,
    const float* __restrict__ concept, const float* __restrict__ pred_w,
    const float* __restrict__ pred_b, float* __restrict__ out) {
  int idx = blockIdx.x * 4 + (threadIdx.x >> 6);    // [0, 64*1023)
  int lane = threadIdx.x & 63;
  if (idx >= BB * (SS - 1)) return;
  int b = idx / (SS - 1), t = idx % (SS - 1);
  const float* e = excl + ((size_t)b * SS + t) * Hn;
  const float* r = rnn + ((size_t)b * SS + t) * Hn;
  const float* c = concept + ((size_t)b * SS + t + 1) * DCn;
  float v = e[lane] * pred_w[lane] + e[lane + 64] * pred_w[lane + 64] +
            r[lane] * pred_w[128 + lane] + r[lane + 64] * pred_w[192 + lane] +
            c[lane] * pred_w[256 + lane];
#pragma unroll
  for (int o = 32; o; o >>= 1) v += __shfl_down(v, o);
  if (lane == 0) out[idx] = sigmoid_f(v + pred_b[0]);
}

extern "C" void kernel_launch(void* const* d_in, const int* in_sizes, int n_in,
                              void* d_out, int out_size, void* d_ws, size_t ws_size,
                              hipStream_t stream) {
  const int* qseq = (const int*)d_in[0];
  const int* cseq = (const int*)d_in[1];
  const int* q2c = (const int*)d_in[2];
  const int* q2cm = (const int*)d_in[3];
  const float* cemb = (const float*)d_in[4];
  const float* remb = (const float*)d_in[5];
  const float* mlp_w = (const float*)d_in[6];
  const float* mlp_b = (const float*)d_in[7];
  const float* sim_w = (const float*)d_in[8];
  const float* W_ih = (const float*)d_in[9];
  const float* b_ih = (const float*)d_in[10];
  const float* W_hh = (const float*)d_in[11];
  const float* b_hh = (const float*)d_in[12];
  const float* pred_w = (const float*)d_in[13];
  const float* pred_b = (const float*)d_in[14];
  float* out = (float*)d_out;

  // workspace layout (f32 element offsets)
  float* ws = (float*)d_ws;
  float* concept = ws;                       // [B,S,64]  f32   [0, 4194304)
  ushort* interb = (ushort*)(ws + 4194304);  // [B,S,128] bf16  [4194304, 8388608)
  ushort* Xp = (ushort*)(ws + 8388608);      // [B,S,384] bf16  [8388608, 20971520)
  float* rnn = ws + 20971520;                // [B,S,128] f32   [20971520, 29360128)
  ushort* Wihb = (ushort*)(ws + 29360128);   // 49152 bf16      [29360128, +24576)
  ushort* mlpwb = (ushort*)(ws + 29384704);  // 16384 bf16      [29384704, +8192)
  float* tmpA = ws + 29392896;               // [B,S,128] f32   [29392896, 37781504)
  float* sbuf = ws + 4194304;                // alias: inter dead after B1
  float* excl = ws + 8388608;                // alias: Xp dead after gru

  convw_kernel<<<256, 256, 0, stream>>>(W_ih, mlp_w, Wihb, mlpwb);
  embed_kernel<<<32768, 256, 0, stream>>>(qseq, cseq, q2c, q2cm, cemb, remb,
                                          interb, concept);
  gemm_mfma_kernel<false, true><<<dim3(1024, 6), 256, 0, stream>>>(
      interb, Wihb, b_ih, Xp, 384);
  gru_kernel<<<64, 512, 0, stream>>>(Xp, W_hh, b_hh, rnn);
  gemm_mfma_kernel<true, false><<<dim3(1024, 2), 256, 0, stream>>>(
      rnn, mlpwb, mlp_b, tmpA, 128);
  score_kernel<<<16384, 256, 0, stream>>>(tmpA, sim_w, sbuf);
  attn_kernel<<<128, 64, 0, stream>>>(sbuf, rnn, excl);
  out_kernel<<<16368, 256, 0, stream>>>(excl, rnn, concept, pred_w, pred_b, out);
}

// Round 11
// 618.042 us; speedup vs baseline: 2.3544x; 1.2250x over previous
//
#include <hip/hip_runtime.h>
#include <hip/hip_bf16.h>
#include <cstdint>

// Problem constants
#define BB 64
#define SS 1024
#define DCn 64
#define Hn 128
#define G3 384

using f32x4 = __attribute__((ext_vector_type(4))) float;
using bf16x8 = __attribute__((ext_vector_type(8))) short;

// rcp-based sigmoid: avoids IEEE div sequence (~12 VALU instr) per call
__device__ __forceinline__ float sigmoid_f(float x) {
  return __builtin_amdgcn_rcpf(1.0f + __expf(-x));
}
__device__ __forceinline__ float tanh_f(float x) {
  float xc = fminf(fmaxf(x, -15.0f), 15.0f);
  float t = __expf(-2.0f * xc);
  return (1.0f - t) * __builtin_amdgcn_rcpf(1.0f + t);
}
__device__ __forceinline__ short f2bf(float x) {
  union { float f; uint32_t u; } v; v.f = x;
  uint32_t r = v.u + 0x7FFFu + ((v.u >> 16) & 1u);   // RNE
  return (short)(r >> 16);
}
__device__ __forceinline__ float bf2f(ushort u) {
  union { uint32_t i; float f; } v; v.i = (uint32_t)u << 16; return v.f;
}
// compile-time-indexed 2-level select (no runtime array index -> no scratch)
__device__ __forceinline__ float sel4(f32x4 v, int q) {
  float t0 = (q & 1) ? v[1] : v[0];
  float t1 = (q & 1) ? v[3] : v[2];
  return (q & 2) ? t1 : t0;
}

// LDS-only barrier: does NOT drain vmcnt -> global loads/stores stay in
// flight across steps.
#define LDS_BARRIER() do {                                   \
    asm volatile("s_waitcnt lgkmcnt(0)" ::: "memory");       \
    __builtin_amdgcn_s_barrier();                            \
    __builtin_amdgcn_sched_barrier(0);                       \
  } while (0)

// ---------------- weight conversion: W_ih, mlp_w -> bf16 (once per call)
__global__ __launch_bounds__(256) void convw_kernel(
    const float* __restrict__ W_ih, const float* __restrict__ mlp_w,
    ushort* __restrict__ Wihb, ushort* __restrict__ mlpwb) {
  int i = blockIdx.x * 256 + threadIdx.x;      // [0, 65536)
  if (i < 49152) Wihb[i] = (ushort)f2bf(W_ih[i]);
  else mlpwb[i - 49152] = (ushort)f2bf(mlp_w[i - 49152]);
}

// ---------------- Phase A: embeddings + conditional concat -> inter(bf16), concept(f32)
__global__ __launch_bounds__(256) void embed_kernel(
    const int* __restrict__ qseq, const int* __restrict__ cseq,
    const int* __restrict__ q2c, const int* __restrict__ q2cm,
    const float* __restrict__ cemb, const float* __restrict__ remb,
    ushort* __restrict__ interb, float* __restrict__ concept) {
  int pos = blockIdx.x * 2 + (threadIdx.x >> 7);   // [0, 65536)
  int d = threadIdx.x & 127;
  int q = qseq[pos];
  int corr = cseq[pos];
  float val;
  if (d < 64) {
    float acc = 0.f, msum = 0.f;
#pragma unroll
    for (int c = 0; c < 4; ++c) {
      int id = q2c[q * 4 + c];
      float m = (float)q2cm[q * 4 + c];
      acc += m * cemb[id * 64 + d];
      msum += m;
    }
    val = acc / fmaxf(msum, 1.0f);
    concept[(size_t)pos * 64 + d] = val;
  } else {
    val = remb[corr * 64 + (d - 64)];
  }
  // corr==1: [concept|corr]  else [corr|concept]
  int slot = (corr == 1) ? d : ((d < 64) ? d + 64 : d - 64);
  interb[(size_t)pos * 128 + slot] = (ushort)f2bf(val);
}

// ---------------- MFMA GEMM: C[M,N] = A[M,128] * Bm[N,128]^T + bias[N]
// 64x64 tile, K=128 one-shot, 256 threads. Same-k-mapping A/B fragments.
template <bool AF32, bool OUTBF>
__global__ __launch_bounds__(256) void gemm_mfma_kernel(
    const void* __restrict__ Ap, const ushort* __restrict__ Bp,
    const float* __restrict__ bias, void* __restrict__ Cp, int N) {
  __shared__ bf16x8 Al[64][16];
  __shared__ bf16x8 Bl[64][16];
  const int m0 = blockIdx.x * 64, n0 = blockIdx.y * 64;
  const int tid = threadIdx.x;
  const int row = tid >> 2, j0 = (tid & 3) * 4;
  if (AF32) {
    const float* A = (const float*)Ap + (size_t)(m0 + row) * 128 + j0 * 8;
#pragma unroll
    for (int jj = 0; jj < 4; ++jj) {
      f32x4 lo = *(const f32x4*)(A + jj * 8);
      f32x4 hi = *(const f32x4*)(A + jj * 8 + 4);
      bf16x8 v;
#pragma unroll
      for (int q = 0; q < 4; ++q) { v[q] = f2bf(lo[q]); v[4 + q] = f2bf(hi[q]); }
      Al[row][(j0 + jj) ^ (row & 15)] = v;
    }
  } else {
    const bf16x8* A = (const bf16x8*)Ap + (size_t)(m0 + row) * 16 + j0;
#pragma unroll
    for (int jj = 0; jj < 4; ++jj) Al[row][(j0 + jj) ^ (row & 15)] = A[jj];
  }
  {
    const bf16x8* Bg = (const bf16x8*)Bp + (size_t)(n0 + row) * 16 + j0;
#pragma unroll
    for (int jj = 0; jj < 4; ++jj) Bl[row][(j0 + jj) ^ (row & 15)] = Bg[jj];
  }
  __syncthreads();
  const int w = tid >> 6, lane = tid & 63, ln = lane & 15, cc = lane >> 4;
  bf16x8 bf[4];
#pragma unroll
  for (int ks = 0; ks < 4; ++ks) bf[ks] = Bl[w * 16 + ln][(ks * 4 + cc) ^ ln];
  f32x4 C0 = {0,0,0,0}, C1 = {0,0,0,0}, C2 = {0,0,0,0}, C3 = {0,0,0,0};
#pragma unroll
  for (int ks = 0; ks < 4; ++ks) {
    bf16x8 a0 = Al[0 * 16 + ln][(ks * 4 + cc) ^ ln];
    bf16x8 a1 = Al[1 * 16 + ln][(ks * 4 + cc) ^ ln];
    bf16x8 a2 = Al[2 * 16 + ln][(ks * 4 + cc) ^ ln];
    bf16x8 a3 = Al[3 * 16 + ln][(ks * 4 + cc) ^ ln];
    C0 = __builtin_amdgcn_mfma_f32_16x16x32_bf16(a0, bf[ks], C0, 0, 0, 0);
    C1 = __builtin_amdgcn_mfma_f32_16x16x32_bf16(a1, bf[ks], C1, 0, 0, 0);
    C2 = __builtin_amdgcn_mfma_f32_16x16x32_bf16(a2, bf[ks], C2, 0, 0, 0);
    C3 = __builtin_amdgcn_mfma_f32_16x16x32_bf16(a3, bf[ks], C3, 0, 0, 0);
  }
  const float bv = bias[n0 + w * 16 + ln];
  const size_t ncol = n0 + w * 16 + ln;
#pragma unroll
  for (int rt = 0; rt < 4; ++rt) {
    f32x4 Cf = (rt == 0) ? C0 : (rt == 1) ? C1 : (rt == 2) ? C2 : C3;
#pragma unroll
    for (int q = 0; q < 4; ++q) {
      float v = Cf[q] + bv;
      size_t idx = (size_t)(m0 + rt * 16 + cc * 4 + q) * N + ncol;
      if (OUTBF) ((ushort*)Cp)[idx] = (ushort)f2bf(v);
      else ((float*)Cp)[idx] = v;
    }
  }
}

// ---------------- Phase C: MFMA GRU. 64 blocks x 1 batch, 512 threads.
// R11: 2-step unroll (compile-time buffer indices), pointer-bump addressing,
// rcp-based sigmoid. Structure otherwise verified R6-R10.
__global__ __attribute__((amdgpu_flat_work_group_size(512, 512)))
__attribute__((amdgpu_waves_per_eu(2, 2))) void gru_kernel(
    const ushort* __restrict__ Xp, const float* __restrict__ W_hh,
    const float* __restrict__ b_hh, float* __restrict__ rnn_out) {
  const int tid = threadIdx.x;
  const int w = tid >> 6;          // wave 0..7 -> h-dims [w*16, w*16+16)
  const int lane = tid & 63;
  const int ln = lane & 15;        // W row within tile / duplicate batch col
  const int c = lane >> 4;         // k-group & row-quad 0..3
  const int qs = ln & 3;           // this lane's selected q
  const int b = blockIdx.x;        // one batch per block

  __shared__ alignas(16) short hlds[2][128];   // bf16 h, double-buffered

  bf16x8 wf[3][4];
#pragma unroll
  for (int gt = 0; gt < 3; ++gt) {
    const float* wr = W_hh + (size_t)(gt * 128 + w * 16 + ln) * 128 + c * 8;
#pragma unroll
    for (int ks = 0; ks < 4; ++ks) {
      bf16x8 f;
#pragma unroll
      for (int j = 0; j < 8; ++j) f[j] = f2bf(wr[ks * 32 + j]);
      wf[gt][ks] = f;
    }
  }
  const f32x4 br = *(const f32x4*)(b_hh + w * 16 + c * 4);
  const f32x4 bz = *(const f32x4*)(b_hh + 128 + w * 16 + c * 4);
  const f32x4 bn = *(const f32x4*)(b_hh + 256 + w * 16 + c * 4);

  if (tid < 128) hlds[0][tid] = 0;             // h(-1) = 0

  const int dim = w * 16 + c * 4 + qs;         // this lane's h-dim
  const ushort* xs = Xp + (size_t)b * SS * G3 + dim;
  float* rsp = rnn_out + (size_t)b * SS * Hn + w * 16 + c * 4 + ln; // ln<4

  // depth-2 prefetch state: set0 feeds even steps, set1 odd steps
  ushort xr0 = xs[0], xz0 = xs[128], xn0 = xs[256];
  ushort xr1 = xs[G3 + 0], xz1 = xs[G3 + 128], xn1 = xs[G3 + 256];
  const ushort* xpf = xs + 2 * (size_t)G3;     // prefetch cursor (t+2)

  float h_old = 0.0f;
  LDS_BARRIER();

  // one GRU half-step: reads hlds[RB], publishes hlds[RB^1].
  // xr/xz/xn consumed then refilled from xpf (branch-free overrun into
  // allocated scratch past Xp on the final iterations -- values unread).
#define GRU_STEP(RB, XR, XZ, XN)                                             \
  {                                                                          \
    const short* hr = hlds[RB];                                              \
    bf16x8 h0 = *(const bf16x8*)(hr + 0 * 32 + c * 8);                       \
    bf16x8 h1 = *(const bf16x8*)(hr + 1 * 32 + c * 8);                       \
    bf16x8 h2 = *(const bf16x8*)(hr + 2 * 32 + c * 8);                       \
    bf16x8 h3 = *(const bf16x8*)(hr + 3 * 32 + c * 8);                       \
    ushort pr = xpf[0], pz = xpf[128], pn = xpf[256];                        \
    xpf += G3;                                                               \
    __builtin_amdgcn_s_setprio(1);                                           \
    f32x4 ar = br, az = bz, an = bn;                                         \
    ar = __builtin_amdgcn_mfma_f32_16x16x32_bf16(wf[0][0], h0, ar, 0, 0, 0); \
    az = __builtin_amdgcn_mfma_f32_16x16x32_bf16(wf[1][0], h0, az, 0, 0, 0); \
    an = __builtin_amdgcn_mfma_f32_16x16x32_bf16(wf[2][0], h0, an, 0, 0, 0); \
    ar = __builtin_amdgcn_mfma_f32_16x16x32_bf16(wf[0][1], h1, ar, 0, 0, 0); \
    az = __builtin_amdgcn_mfma_f32_16x16x32_bf16(wf[1][1], h1, az, 0, 0, 0); \
    an = __builtin_amdgcn_mfma_f32_16x16x32_bf16(wf[2][1], h1, an, 0, 0, 0); \
    ar = __builtin_amdgcn_mfma_f32_16x16x32_bf16(wf[0][2], h2, ar, 0, 0, 0); \
    az = __builtin_amdgcn_mfma_f32_16x16x32_bf16(wf[1][2], h2, az, 0, 0, 0); \
    an = __builtin_amdgcn_mfma_f32_16x16x32_bf16(wf[2][2], h2, an, 0, 0, 0); \
    ar = __builtin_amdgcn_mfma_f32_16x16x32_bf16(wf[0][3], h3, ar, 0, 0, 0); \
    az = __builtin_amdgcn_mfma_f32_16x16x32_bf16(wf[1][3], h3, az, 0, 0, 0); \
    an = __builtin_amdgcn_mfma_f32_16x16x32_bf16(wf[2][3], h3, an, 0, 0, 0); \
    __builtin_amdgcn_s_setprio(0);                                           \
    float ga = sel4(ar, qs), gz = sel4(az, qs), gn = sel4(an, qs);           \
    float r = sigmoid_f(bf2f(XR) + ga);                                      \
    float z = sigmoid_f(bf2f(XZ) + gz);                                      \
    float a = bf2f(XN) + r * gn;                                             \
    float e = __expf(-2.0f * a);                                             \
    float n = 2.0f * __builtin_amdgcn_rcpf(1.0f + e) - 1.0f;                 \
    float hn = n + z * (h_old - n);                                          \
    h_old = hn;                                                              \
    if (ln < 4) hlds[RB ^ 1][w * 16 + c * 4 + ln] = f2bf(hn);                \
    LDS_BARRIER();                                                           \
    if (ln < 4) *rsp = hn;                                                   \
    rsp += Hn;                                                               \
    XR = pr; XZ = pz; XN = pn;                                               \
  }

  for (int t = 0; t < SS; t += 2) {
    GRU_STEP(0, xr0, xz0, xn0)
    GRU_STEP(1, xr1, xz1, xn1)
  }
#undef GRU_STEP
}

// ---------------- Phase D2: s[pos] = sum_a tanh(tmpA[pos,a]) * sim_w[a]
__global__ __launch_bounds__(256) void score_kernel(
    const float* __restrict__ tmpA, const float* __restrict__ sim_w,
    float* __restrict__ s) {
  int pos = blockIdx.x * 4 + (threadIdx.x >> 6);
  int lane = threadIdx.x & 63;
  const float* row = tmpA + (size_t)pos * 128;
  float v = tanh_f(row[lane]) * sim_w[lane] +
            tanh_f(row[lane + 64]) * sim_w[lane + 64];
#pragma unroll
  for (int o = 32; o; o >>= 1) v += __shfl_down(v, o);
  if (lane == 0) s[pos] = v;
}

// ---------------- Phase E: cumulative softmax-average + exclusive cumsum.
// 128 blocks (b x h-half) x 64 threads.
__global__ __launch_bounds__(64) void attn_kernel(
    const float* __restrict__ s, const float* __restrict__ rnn,
    float* __restrict__ excl) {
  const int b = blockIdx.x >> 1;
  const int h = ((blockIdx.x & 1) << 6) + threadIdx.x;
  const int tl = threadIdx.x;     // 0..63
  __shared__ float elds[SS];
  const float* sb = s + (size_t)b * SS;
  float m = -1e30f;
  for (int i = tl; i < SS; i += 64) m = fmaxf(m, sb[i]);
#pragma unroll
  for (int o = 32; o; o >>= 1) m = fmaxf(m, __shfl_xor(m, o));
  for (int i = tl; i < SS; i += 64) elds[i] = __expf(sb[i] - m);
  __syncthreads();

  const float* rb = rnn + (size_t)b * SS * Hn + h;
  float* eb = excl + (size_t)b * SS * Hn + h;
  float num = 0.f, den = 0.f, run = 0.f;
  float rcur = rb[0];
  for (int t = 0; t < SS; ++t) {
    float rnxt = (t < SS - 1) ? rb[(size_t)(t + 1) * Hn] : 0.0f;
    float e = elds[t];
    den += e;
    num += e * rcur;
    eb[(size_t)t * Hn] = run;                        // exclusive
    run += num * __builtin_amdgcn_rcpf(den);         // attn_t
    rcur = rnxt;
  }
}

// ---------------- Phase F: logits -> sigmoid. One wave per (b, t).
__global__ __launch_bounds__(256) void out_kernel(
    const float* __restrict__ excl, const float* __restrict__ rnn,
    const float* __restrict__ concept, const float* __restrict__ pred_w,
    const float* __restrict__ pred_b, float* __restrict__ out) {
  int idx = blockIdx.x * 4 + (threadIdx.x >> 6);    // [0, 64*1023)
  int lane = threadIdx.x & 63;
  if (idx >= BB * (SS - 1)) return;
  int b = idx / (SS - 1), t = idx % (SS - 1);
  const float* e = excl + ((size_t)b * SS + t) * Hn;
  const float* r = rnn + ((size_t)b * SS + t) * Hn;
  const float* c = concept + ((size_t)b * SS + t + 1) * DCn;
  float v = e[lane] * pred_w[lane] + e[lane + 64] * pred_w[lane + 64] +
            r[lane] * pred_w[128 + lane] + r[lane + 64] * pred_w[192 + lane] +
            c[lane] * pred_w[256 + lane];
#pragma unroll
  for (int o = 32; o; o >>= 1) v += __shfl_down(v, o);
  if (lane == 0) out[idx] = sigmoid_f(v + pred_b[0]);
}

extern "C" void kernel_launch(void* const* d_in, const int* in_sizes, int n_in,
                              void* d_out, int out_size, void* d_ws, size_t ws_size,
                              hipStream_t stream) {
  const int* qseq = (const int*)d_in[0];
  const int* cseq = (const int*)d_in[1];
  const int* q2c = (const int*)d_in[2];
  const int* q2cm = (const int*)d_in[3];
  const float* cemb = (const float*)d_in[4];
  const float* remb = (const float*)d_in[5];
  const float* mlp_w = (const float*)d_in[6];
  const float* mlp_b = (const float*)d_in[7];
  const float* sim_w = (const float*)d_in[8];
  const float* W_ih = (const float*)d_in[9];
  const float* b_ih = (const float*)d_in[10];
  const float* W_hh = (const float*)d_in[11];
  const float* b_hh = (const float*)d_in[12];
  const float* pred_w = (const float*)d_in[13];
  const float* pred_b = (const float*)d_in[14];
  float* out = (float*)d_out;

  // workspace layout (f32 element offsets)
  float* ws = (float*)d_ws;
  float* concept = ws;                       // [B,S,64]  f32   [0, 4194304)
  ushort* interb = (ushort*)(ws + 4194304);  // [B,S,128] bf16  [4194304, 8388608)
  ushort* Xp = (ushort*)(ws + 8388608);      // [B,S,384] bf16  [8388608, 20971520)
  float* rnn = ws + 20971520;                // [B,S,128] f32   [20971520, 29360128)
  ushort* Wihb = (ushort*)(ws + 29360128);   // 49152 bf16      [29360128, +24576)
  ushort* mlpwb = (ushort*)(ws + 29384704);  // 16384 bf16      [29384704, +8192)
  float* tmpA = ws + 29392896;               // [B,S,128] f32   [29392896, 37781504)
  float* sbuf = ws + 4194304;                // alias: inter dead after B1
  float* excl = ws + 8388608;                // alias: Xp dead after gru

  convw_kernel<<<256, 256, 0, stream>>>(W_ih, mlp_w, Wihb, mlpwb);
  embed_kernel<<<32768, 256, 0, stream>>>(qseq, cseq, q2c, q2cm, cemb, remb,
                                          interb, concept);
  gemm_mfma_kernel<false, true><<<dim3(1024, 6), 256, 0, stream>>>(
      interb, Wihb, b_ih, Xp, 384);
  gru_kernel<<<64, 512, 0, stream>>>(Xp, W_hh, b_hh, rnn);
  gemm_mfma_kernel<true, false><<<dim3(1024, 2), 256, 0, stream>>>(
      rnn, mlpwb, mlp_b, tmpA, 128);
  score_kernel<<<16384, 256, 0, stream>>>(tmpA, sim_w, sbuf);
  attn_kernel<<<128, 64, 0, stream>>>(sbuf, rnn, excl);
  out_kernel<<<16368, 256, 0, stream>>>(excl, rnn, concept, pred_w, pred_b, out);
}

// Round 12
// 583.781 us; speedup vs baseline: 2.4925x; 1.0587x over previous
//
#include <hip/hip_runtime.h>
#include <hip/hip_bf16.h>
#include <cstdint>

// Problem constants
#define BB 64
#define SS 1024
#define DCn 64
#define Hn 128
#define G3 384
#define HPITCH 136   // shorts per h-row in LDS: 272B == 16 mod 128 -> <=2-way banks

using f32x4 = __attribute__((ext_vector_type(4))) float;
using bf16x8 = __attribute__((ext_vector_type(8))) short;

// rcp-based sigmoid: avoids IEEE div sequence (~12 VALU instr) per call
__device__ __forceinline__ float sigmoid_f(float x) {
  return __builtin_amdgcn_rcpf(1.0f + __expf(-x));
}
__device__ __forceinline__ float tanh_f(float x) {
  float xc = fminf(fmaxf(x, -15.0f), 15.0f);
  float t = __expf(-2.0f * xc);
  return (1.0f - t) * __builtin_amdgcn_rcpf(1.0f + t);
}
__device__ __forceinline__ short f2bf(float x) {
  union { float f; uint32_t u; } v; v.f = x;
  uint32_t r = v.u + 0x7FFFu + ((v.u >> 16) & 1u);   // RNE
  return (short)(r >> 16);
}
__device__ __forceinline__ float bf2f(ushort u) {
  union { uint32_t i; float f; } v; v.i = (uint32_t)u << 16; return v.f;
}
// compile-time-indexed 2-level select (no runtime array index -> no scratch)
__device__ __forceinline__ float sel4(f32x4 v, int q) {
  float t0 = (q & 1) ? v[1] : v[0];
  float t1 = (q & 1) ? v[3] : v[2];
  return (q & 2) ? t1 : t0;
}

// LDS-only barrier: does NOT drain vmcnt -> global loads/stores stay in
// flight across steps.
#define LDS_BARRIER() do {                                   \
    asm volatile("s_waitcnt lgkmcnt(0)" ::: "memory");       \
    __builtin_amdgcn_s_barrier();                            \
    __builtin_amdgcn_sched_barrier(0);                       \
  } while (0)

// ---------------- weight conversion: W_ih, mlp_w -> bf16 (once per call)
__global__ __launch_bounds__(256) void convw_kernel(
    const float* __restrict__ W_ih, const float* __restrict__ mlp_w,
    ushort* __restrict__ Wihb, ushort* __restrict__ mlpwb) {
  int i = blockIdx.x * 256 + threadIdx.x;      // [0, 65536)
  if (i < 49152) Wihb[i] = (ushort)f2bf(W_ih[i]);
  else mlpwb[i - 49152] = (ushort)f2bf(mlp_w[i - 49152]);
}

// ---------------- Phase A: embeddings + conditional concat -> inter(bf16), concept(f32)
__global__ __launch_bounds__(256) void embed_kernel(
    const int* __restrict__ qseq, const int* __restrict__ cseq,
    const int* __restrict__ q2c, const int* __restrict__ q2cm,
    const float* __restrict__ cemb, const float* __restrict__ remb,
    ushort* __restrict__ interb, float* __restrict__ concept) {
  int pos = blockIdx.x * 2 + (threadIdx.x >> 7);   // [0, 65536)
  int d = threadIdx.x & 127;
  int q = qseq[pos];
  int corr = cseq[pos];
  float val;
  if (d < 64) {
    float acc = 0.f, msum = 0.f;
#pragma unroll
    for (int c = 0; c < 4; ++c) {
      int id = q2c[q * 4 + c];
      float m = (float)q2cm[q * 4 + c];
      acc += m * cemb[id * 64 + d];
      msum += m;
    }
    val = acc / fmaxf(msum, 1.0f);
    concept[(size_t)pos * 64 + d] = val;
  } else {
    val = remb[corr * 64 + (d - 64)];
  }
  // corr==1: [concept|corr]  else [corr|concept]
  int slot = (corr == 1) ? d : ((d < 64) ? d + 64 : d - 64);
  interb[(size_t)pos * 128 + slot] = (ushort)f2bf(val);
}

// ---------------- MFMA GEMM: C[M,N] = A[M,128] * Bm[N,128]^T + bias[N]
// 64x64 tile, K=128 one-shot, 256 threads. Same-k-mapping A/B fragments.
template <bool AF32, bool OUTBF>
__global__ __launch_bounds__(256) void gemm_mfma_kernel(
    const void* __restrict__ Ap, const ushort* __restrict__ Bp,
    const float* __restrict__ bias, void* __restrict__ Cp, int N) {
  __shared__ bf16x8 Al[64][16];
  __shared__ bf16x8 Bl[64][16];
  const int m0 = blockIdx.x * 64, n0 = blockIdx.y * 64;
  const int tid = threadIdx.x;
  const int row = tid >> 2, j0 = (tid & 3) * 4;
  if (AF32) {
    const float* A = (const float*)Ap + (size_t)(m0 + row) * 128 + j0 * 8;
#pragma unroll
    for (int jj = 0; jj < 4; ++jj) {
      f32x4 lo = *(const f32x4*)(A + jj * 8);
      f32x4 hi = *(const f32x4*)(A + jj * 8 + 4);
      bf16x8 v;
#pragma unroll
      for (int q = 0; q < 4; ++q) { v[q] = f2bf(lo[q]); v[4 + q] = f2bf(hi[q]); }
      Al[row][(j0 + jj) ^ (row & 15)] = v;
    }
  } else {
    const bf16x8* A = (const bf16x8*)Ap + (size_t)(m0 + row) * 16 + j0;
#pragma unroll
    for (int jj = 0; jj < 4; ++jj) Al[row][(j0 + jj) ^ (row & 15)] = A[jj];
  }
  {
    const bf16x8* Bg = (const bf16x8*)Bp + (size_t)(n0 + row) * 16 + j0;
#pragma unroll
    for (int jj = 0; jj < 4; ++jj) Bl[row][(j0 + jj) ^ (row & 15)] = Bg[jj];
  }
  __syncthreads();
  const int w = tid >> 6, lane = tid & 63, ln = lane & 15, cc = lane >> 4;
  bf16x8 bf[4];
#pragma unroll
  for (int ks = 0; ks < 4; ++ks) bf[ks] = Bl[w * 16 + ln][(ks * 4 + cc) ^ ln];
  f32x4 C0 = {0,0,0,0}, C1 = {0,0,0,0}, C2 = {0,0,0,0}, C3 = {0,0,0,0};
#pragma unroll
  for (int ks = 0; ks < 4; ++ks) {
    bf16x8 a0 = Al[0 * 16 + ln][(ks * 4 + cc) ^ ln];
    bf16x8 a1 = Al[1 * 16 + ln][(ks * 4 + cc) ^ ln];
    bf16x8 a2 = Al[2 * 16 + ln][(ks * 4 + cc) ^ ln];
    bf16x8 a3 = Al[3 * 16 + ln][(ks * 4 + cc) ^ ln];
    C0 = __builtin_amdgcn_mfma_f32_16x16x32_bf16(a0, bf[ks], C0, 0, 0, 0);
    C1 = __builtin_amdgcn_mfma_f32_16x16x32_bf16(a1, bf[ks], C1, 0, 0, 0);
    C2 = __builtin_amdgcn_mfma_f32_16x16x32_bf16(a2, bf[ks], C2, 0, 0, 0);
    C3 = __builtin_amdgcn_mfma_f32_16x16x32_bf16(a3, bf[ks], C3, 0, 0, 0);
  }
  const float bv = bias[n0 + w * 16 + ln];
  const size_t ncol = n0 + w * 16 + ln;
#pragma unroll
  for (int rt = 0; rt < 4; ++rt) {
    f32x4 Cf = (rt == 0) ? C0 : (rt == 1) ? C1 : (rt == 2) ? C2 : C3;
#pragma unroll
    for (int q = 0; q < 4; ++q) {
      float v = Cf[q] + bv;
      size_t idx = (size_t)(m0 + rt * 16 + cc * 4 + q) * N + ncol;
      if (OUTBF) ((ushort*)Cp)[idx] = (ushort)f2bf(v);
      else ((float*)Cp)[idx] = v;
    }
  }
}

// ---------------- Phase C: MFMA GRU. 16 blocks x 4 REAL batches, 512 threads.
// R12: B-columns carry 4 real batches (col ln -> batch ln&3; verified col
// semantics from R6's 16-real-batch run). Per lane ONE real gate triple:
// batch = ln&3, row-q = ln>>2 -> dim = w*16 + c*4 + (ln>>2). The 96
// MFMAs/block-step (466 cyc/SIMD matrix time) now cover 4 batch-steps.
// h state: hlds[2][4][HPITCH] bf16, 272B pitch (<=2-way bank aliasing, free).
// Per-CU Xp stream: 3KB/step (~307 cyc), prefetch-hidden.
__global__ __attribute__((amdgpu_flat_work_group_size(512, 512)))
__attribute__((amdgpu_waves_per_eu(2, 2))) void gru_kernel(
    const ushort* __restrict__ Xp, const float* __restrict__ W_hh,
    const float* __restrict__ b_hh, float* __restrict__ rnn_out) {
  const int tid = threadIdx.x;
  const int w = tid >> 6;          // wave 0..7 -> h-dims [w*16, w*16+16)
  const int lane = tid & 63;
  const int ln = lane & 15;        // W row within tile; batch col = ln&3
  const int c = lane >> 4;         // k-group & row-quad 0..3
  const int bl = ln & 3;           // this lane's batch (0..3)
  const int qs = ln >> 2;          // this lane's C-reg / row-within-quad
  const int b0 = blockIdx.x * 4;   // four batches per block

  __shared__ alignas(16) short hlds[2][4 * HPITCH];  // bf16 h, dbuf x 4 batches

  bf16x8 wf[3][4];
#pragma unroll
  for (int gt = 0; gt < 3; ++gt) {
    const float* wr = W_hh + (size_t)(gt * 128 + w * 16 + ln) * 128 + c * 8;
#pragma unroll
    for (int ks = 0; ks < 4; ++ks) {
      bf16x8 f;
#pragma unroll
      for (int j = 0; j < 8; ++j) f[j] = f2bf(wr[ks * 32 + j]);
      wf[gt][ks] = f;
    }
  }
  const f32x4 br = *(const f32x4*)(b_hh + w * 16 + c * 4);
  const f32x4 bz = *(const f32x4*)(b_hh + 128 + w * 16 + c * 4);
  const f32x4 bn = *(const f32x4*)(b_hh + 256 + w * 16 + c * 4);

  // zero both h buffers (1088 shorts = 544 dwords)
  for (int i = tid; i < 544; i += 512) ((uint32_t*)hlds)[i] = 0;

  const int dim = w * 16 + c * 4 + qs;         // this lane's h-dim
  const ushort* xs = Xp + (size_t)(b0 + bl) * SS * G3 + dim;
  float* rsp = rnn_out + (size_t)(b0 + bl) * SS * Hn + dim;

  // depth-2 prefetch state: set0 feeds even steps, set1 odd steps
  ushort xr0 = xs[0], xz0 = xs[128], xn0 = xs[256];
  ushort xr1 = xs[G3 + 0], xz1 = xs[G3 + 128], xn1 = xs[G3 + 256];
  const ushort* xpf = xs + 2 * (size_t)G3;     // prefetch cursor (t+2)

  float h_old = 0.0f;
  LDS_BARRIER();

  // one GRU half-step: reads hlds[RB], publishes hlds[RB^1].
  // xr/xz/xn consumed then refilled from xpf (branch-free overrun into
  // allocated scratch past Xp on the final iterations -- values unread).
#define GRU_STEP(RB, XR, XZ, XN)                                             \
  {                                                                          \
    const short* hr = hlds[RB] + bl * HPITCH;                                \
    bf16x8 h0 = *(const bf16x8*)(hr + 0 * 32 + c * 8);                       \
    bf16x8 h1 = *(const bf16x8*)(hr + 1 * 32 + c * 8);                       \
    bf16x8 h2 = *(const bf16x8*)(hr + 2 * 32 + c * 8);                       \
    bf16x8 h3 = *(const bf16x8*)(hr + 3 * 32 + c * 8);                       \
    ushort pr = xpf[0], pz = xpf[128], pn = xpf[256];                        \
    xpf += G3;                                                               \
    __builtin_amdgcn_s_setprio(1);                                           \
    f32x4 ar = br, az = bz, an = bn;                                         \
    ar = __builtin_amdgcn_mfma_f32_16x16x32_bf16(wf[0][0], h0, ar, 0, 0, 0); \
    az = __builtin_amdgcn_mfma_f32_16x16x32_bf16(wf[1][0], h0, az, 0, 0, 0); \
    an = __builtin_amdgcn_mfma_f32_16x16x32_bf16(wf[2][0], h0, an, 0, 0, 0); \
    ar = __builtin_amdgcn_mfma_f32_16x16x32_bf16(wf[0][1], h1, ar, 0, 0, 0); \
    az = __builtin_amdgcn_mfma_f32_16x16x32_bf16(wf[1][1], h1, az, 0, 0, 0); \
    an = __builtin_amdgcn_mfma_f32_16x16x32_bf16(wf[2][1], h1, an, 0, 0, 0); \
    ar = __builtin_amdgcn_mfma_f32_16x16x32_bf16(wf[0][2], h2, ar, 0, 0, 0); \
    az = __builtin_amdgcn_mfma_f32_16x16x32_bf16(wf[1][2], h2, az, 0, 0, 0); \
    an = __builtin_amdgcn_mfma_f32_16x16x32_bf16(wf[2][2], h2, an, 0, 0, 0); \
    ar = __builtin_amdgcn_mfma_f32_16x16x32_bf16(wf[0][3], h3, ar, 0, 0, 0); \
    az = __builtin_amdgcn_mfma_f32_16x16x32_bf16(wf[1][3], h3, az, 0, 0, 0); \
    an = __builtin_amdgcn_mfma_f32_16x16x32_bf16(wf[2][3], h3, an, 0, 0, 0); \
    __builtin_amdgcn_s_setprio(0);                                           \
    float ga = sel4(ar, qs), gz = sel4(az, qs), gn = sel4(an, qs);           \
    float r = sigmoid_f(bf2f(XR) + ga);                                      \
    float z = sigmoid_f(bf2f(XZ) + gz);                                      \
    float a = bf2f(XN) + r * gn;                                             \
    float e = __expf(-2.0f * a);                                             \
    float n = 2.0f * __builtin_amdgcn_rcpf(1.0f + e) - 1.0f;                 \
    float hn = n + z * (h_old - n);                                          \
    h_old = hn;                                                              \
    hlds[RB ^ 1][bl * HPITCH + dim] = f2bf(hn);                              \
    LDS_BARRIER();                                                           \
    *rsp = hn;                                                               \
    rsp += Hn;                                                               \
    XR = pr; XZ = pz; XN = pn;                                               \
  }

  for (int t = 0; t < SS; t += 2) {
    GRU_STEP(0, xr0, xz0, xn0)
    GRU_STEP(1, xr1, xz1, xn1)
  }
#undef GRU_STEP
}

// ---------------- Phase D2: s[pos] = sum_a tanh(tmpA[pos,a]) * sim_w[a]
__global__ __launch_bounds__(256) void score_kernel(
    const float* __restrict__ tmpA, const float* __restrict__ sim_w,
    float* __restrict__ s) {
  int pos = blockIdx.x * 4 + (threadIdx.x >> 6);
  int lane = threadIdx.x & 63;
  const float* row = tmpA + (size_t)pos * 128;
  float v = tanh_f(row[lane]) * sim_w[lane] +
            tanh_f(row[lane + 64]) * sim_w[lane + 64];
#pragma unroll
  for (int o = 32; o; o >>= 1) v += __shfl_down(v, o);
  if (lane == 0) s[pos] = v;
}

// ---------------- Phase E: cumulative softmax-average + exclusive cumsum.
// 128 blocks (b x h-half) x 64 threads.
__global__ __launch_bounds__(64) void attn_kernel(
    const float* __restrict__ s, const float* __restrict__ rnn,
    float* __restrict__ excl) {
  const int b = blockIdx.x >> 1;
  const int h = ((blockIdx.x & 1) << 6) + threadIdx.x;
  const int tl = threadIdx.x;     // 0..63
  __shared__ float elds[SS];
  const float* sb = s + (size_t)b * SS;
  float m = -1e30f;
  for (int i = tl; i < SS; i += 64) m = fmaxf(m, sb[i]);
#pragma unroll
  for (int o = 32; o; o >>= 1) m = fmaxf(m, __shfl_xor(m, o));
  for (int i = tl; i < SS; i += 64) elds[i] = __expf(sb[i] - m);
  __syncthreads();

  const float* rb = rnn + (size_t)b * SS * Hn + h;
  float* eb = excl + (size_t)b * SS * Hn + h;
  float num = 0.f, den = 0.f, run = 0.f;
  float rcur = rb[0];
  for (int t = 0; t < SS; ++t) {
    float rnxt = (t < SS - 1) ? rb[(size_t)(t + 1) * Hn] : 0.0f;
    float e = elds[t];
    den += e;
    num += e * rcur;
    eb[(size_t)t * Hn] = run;                        // exclusive
    run += num * __builtin_amdgcn_rcpf(den);         // attn_t
    rcur = rnxt;
  }
}

// ---------------- Phase F: logits -> sigmoid. One wave per (b, t).
__global__ __launch_bounds__(256) void out_kernel(
    const float* __restrict__ excl, const float* __restrict__ rnn,
    const float* __restrict__ concept, const float* __restrict__ pred_w,
    const float* __restrict__ pred_b, float* __restrict__ out) {
  int idx = blockIdx.x * 4 + (threadIdx.x >> 6);    // [0, 64*1023)
  int lane = threadIdx.x & 63;
  if (idx >= BB * (SS - 1)) return;
  int b = idx / (SS - 1), t = idx % (SS - 1);
  const float* e = excl + ((size_t)b * SS + t) * Hn;
  const float* r = rnn + ((size_t)b * SS + t) * Hn;
  const float* c = concept + ((size_t)b * SS + t + 1) * DCn;
  float v = e[lane] * pred_w[lane] + e[lane + 64] * pred_w[lane + 64] +
            r[lane] * pred_w[128 + lane] + r[lane + 64] * pred_w[192 + lane] +
            c[lane] * pred_w[256 + lane];
#pragma unroll
  for (int o = 32; o; o >>= 1) v += __shfl_down(v, o);
  if (lane == 0) out[idx] = sigmoid_f(v + pred_b[0]);
}

extern "C" void kernel_launch(void* const* d_in, const int* in_sizes, int n_in,
                              void* d_out, int out_size, void* d_ws, size_t ws_size,
                              hipStream_t stream) {
  const int* qseq = (const int*)d_in[0];
  const int* cseq = (const int*)d_in[1];
  const int* q2c = (const int*)d_in[2];
  const int* q2cm = (const int*)d_in[3];
  const float* cemb = (const float*)d_in[4];
  const float* remb = (const float*)d_in[5];
  const float* mlp_w = (const float*)d_in[6];
  const float* mlp_b = (const float*)d_in[7];
  const float* sim_w = (const float*)d_in[8];
  const float* W_ih = (const float*)d_in[9];
  const float* b_ih = (const float*)d_in[10];
  const float* W_hh = (const float*)d_in[11];
  const float* b_hh = (const float*)d_in[12];
  const float* pred_w = (const float*)d_in[13];
  const float* pred_b = (const float*)d_in[14];
  float* out = (float*)d_out;

  // workspace layout (f32 element offsets)
  float* ws = (float*)d_ws;
  float* concept = ws;                       // [B,S,64]  f32   [0, 4194304)
  ushort* interb = (ushort*)(ws + 4194304);  // [B,S,128] bf16  [4194304, 8388608)
  ushort* Xp = (ushort*)(ws + 8388608);      // [B,S,384] bf16  [8388608, 20971520)
  float* rnn = ws + 20971520;                // [B,S,128] f32   [20971520, 29360128)
  ushort* Wihb = (ushort*)(ws + 29360128);   // 49152 bf16      [29360128, +24576)
  ushort* mlpwb = (ushort*)(ws + 29384704);  // 16384 bf16      [29384704, +8192)
  float* tmpA = ws + 29392896;               // [B,S,128] f32   [29392896, 37781504)
  float* sbuf = ws + 4194304;                // alias: inter dead after B1
  float* excl = ws + 8388608;                // alias: Xp dead after gru

  convw_kernel<<<256, 256, 0, stream>>>(W_ih, mlp_w, Wihb, mlpwb);
  embed_kernel<<<32768, 256, 0, stream>>>(qseq, cseq, q2c, q2cm, cemb, remb,
                                          interb, concept);
  gemm_mfma_kernel<false, true><<<dim3(1024, 6), 256, 0, stream>>>(
      interb, Wihb, b_ih, Xp, 384);
  gru_kernel<<<16, 512, 0, stream>>>(Xp, W_hh, b_hh, rnn);
  gemm_mfma_kernel<true, false><<<dim3(1024, 2), 256, 0, stream>>>(
      rnn, mlpwb, mlp_b, tmpA, 128);
  score_kernel<<<16384, 256, 0, stream>>>(tmpA, sim_w, sbuf);
  attn_kernel<<<128, 64, 0, stream>>>(sbuf, rnn, excl);
  out_kernel<<<16368, 256, 0, stream>>>(excl, rnn, concept, pred_w, pred_b, out);
}

// Round 13
// 572.774 us; speedup vs baseline: 2.5404x; 1.0192x over previous
//
#include <hip/hip_runtime.h>
#include <hip/hip_bf16.h>
#include <cstdint>

// Problem constants
#define BB 64
#define SS 1024
#define DCn 64
#define Hn 128
#define G3 384
#define HPITCH 144   // shorts per h-row: pitch_dw=72 == 8 mod 32 -> reads/writes <=2-way (free)

using f32x4 = __attribute__((ext_vector_type(4))) float;
using bf16x8 = __attribute__((ext_vector_type(8))) short;

// rcp-based sigmoid: avoids IEEE div sequence (~12 VALU instr) per call
__device__ __forceinline__ float sigmoid_f(float x) {
  return __builtin_amdgcn_rcpf(1.0f + __expf(-x));
}
__device__ __forceinline__ float tanh_f(float x) {
  float xc = fminf(fmaxf(x, -15.0f), 15.0f);
  float t = __expf(-2.0f * xc);
  return (1.0f - t) * __builtin_amdgcn_rcpf(1.0f + t);
}
__device__ __forceinline__ short f2bf(float x) {
  union { float f; uint32_t u; } v; v.f = x;
  uint32_t r = v.u + 0x7FFFu + ((v.u >> 16) & 1u);   // RNE
  return (short)(r >> 16);
}
__device__ __forceinline__ float bf2f(ushort u) {
  union { uint32_t i; float f; } v; v.i = (uint32_t)u << 16; return v.f;
}
// compile-time-indexed 2-level select (no runtime array index -> no scratch)
__device__ __forceinline__ float sel4(f32x4 v, int q) {
  float t0 = (q & 1) ? v[1] : v[0];
  float t1 = (q & 1) ? v[3] : v[2];
  return (q & 2) ? t1 : t0;
}

// LDS-only barrier: does NOT drain vmcnt -> global loads/stores stay in
// flight across steps.
#define LDS_BARRIER() do {                                   \
    asm volatile("s_waitcnt lgkmcnt(0)" ::: "memory");       \
    __builtin_amdgcn_s_barrier();                            \
    __builtin_amdgcn_sched_barrier(0);                       \
  } while (0)

// ---------------- weight conversion: W_ih, mlp_w -> bf16 (once per call)
__global__ __launch_bounds__(256) void convw_kernel(
    const float* __restrict__ W_ih, const float* __restrict__ mlp_w,
    ushort* __restrict__ Wihb, ushort* __restrict__ mlpwb) {
  int i = blockIdx.x * 256 + threadIdx.x;      // [0, 65536)
  if (i < 49152) Wihb[i] = (ushort)f2bf(W_ih[i]);
  else mlpwb[i - 49152] = (ushort)f2bf(mlp_w[i - 49152]);
}

// ---------------- Phase A: embeddings + conditional concat -> inter(bf16), concept(f32)
__global__ __launch_bounds__(256) void embed_kernel(
    const int* __restrict__ qseq, const int* __restrict__ cseq,
    const int* __restrict__ q2c, const int* __restrict__ q2cm,
    const float* __restrict__ cemb, const float* __restrict__ remb,
    ushort* __restrict__ interb, float* __restrict__ concept) {
  int pos = blockIdx.x * 2 + (threadIdx.x >> 7);   // [0, 65536)
  int d = threadIdx.x & 127;
  int q = qseq[pos];
  int corr = cseq[pos];
  float val;
  if (d < 64) {
    float acc = 0.f, msum = 0.f;
#pragma unroll
    for (int c = 0; c < 4; ++c) {
      int id = q2c[q * 4 + c];
      float m = (float)q2cm[q * 4 + c];
      acc += m * cemb[id * 64 + d];
      msum += m;
    }
    val = acc / fmaxf(msum, 1.0f);
    concept[(size_t)pos * 64 + d] = val;
  } else {
    val = remb[corr * 64 + (d - 64)];
  }
  // corr==1: [concept|corr]  else [corr|concept]
  int slot = (corr == 1) ? d : ((d < 64) ? d + 64 : d - 64);
  interb[(size_t)pos * 128 + slot] = (ushort)f2bf(val);
}

// ---------------- MFMA GEMM: C[M,N] = A[M,128] * Bm[N,128]^T + bias[N]
// 64x64 tile, K=128 one-shot, 256 threads. Same-k-mapping A/B fragments.
template <bool AF32, bool OUTBF>
__global__ __launch_bounds__(256) void gemm_mfma_kernel(
    const void* __restrict__ Ap, const ushort* __restrict__ Bp,
    const float* __restrict__ bias, void* __restrict__ Cp, int N) {
  __shared__ bf16x8 Al[64][16];
  __shared__ bf16x8 Bl[64][16];
  const int m0 = blockIdx.x * 64, n0 = blockIdx.y * 64;
  const int tid = threadIdx.x;
  const int row = tid >> 2, j0 = (tid & 3) * 4;
  if (AF32) {
    const float* A = (const float*)Ap + (size_t)(m0 + row) * 128 + j0 * 8;
#pragma unroll
    for (int jj = 0; jj < 4; ++jj) {
      f32x4 lo = *(const f32x4*)(A + jj * 8);
      f32x4 hi = *(const f32x4*)(A + jj * 8 + 4);
      bf16x8 v;
#pragma unroll
      for (int q = 0; q < 4; ++q) { v[q] = f2bf(lo[q]); v[4 + q] = f2bf(hi[q]); }
      Al[row][(j0 + jj) ^ (row & 15)] = v;
    }
  } else {
    const bf16x8* A = (const bf16x8*)Ap + (size_t)(m0 + row) * 16 + j0;
#pragma unroll
    for (int jj = 0; jj < 4; ++jj) Al[row][(j0 + jj) ^ (row & 15)] = A[jj];
  }
  {
    const bf16x8* Bg = (const bf16x8*)Bp + (size_t)(n0 + row) * 16 + j0;
#pragma unroll
    for (int jj = 0; jj < 4; ++jj) Bl[row][(j0 + jj) ^ (row & 15)] = Bg[jj];
  }
  __syncthreads();
  const int w = tid >> 6, lane = tid & 63, ln = lane & 15, cc = lane >> 4;
  bf16x8 bf[4];
#pragma unroll
  for (int ks = 0; ks < 4; ++ks) bf[ks] = Bl[w * 16 + ln][(ks * 4 + cc) ^ ln];
  f32x4 C0 = {0,0,0,0}, C1 = {0,0,0,0}, C2 = {0,0,0,0}, C3 = {0,0,0,0};
#pragma unroll
  for (int ks = 0; ks < 4; ++ks) {
    bf16x8 a0 = Al[0 * 16 + ln][(ks * 4 + cc) ^ ln];
    bf16x8 a1 = Al[1 * 16 + ln][(ks * 4 + cc) ^ ln];
    bf16x8 a2 = Al[2 * 16 + ln][(ks * 4 + cc) ^ ln];
    bf16x8 a3 = Al[3 * 16 + ln][(ks * 4 + cc) ^ ln];
    C0 = __builtin_amdgcn_mfma_f32_16x16x32_bf16(a0, bf[ks], C0, 0, 0, 0);
    C1 = __builtin_amdgcn_mfma_f32_16x16x32_bf16(a1, bf[ks], C1, 0, 0, 0);
    C2 = __builtin_amdgcn_mfma_f32_16x16x32_bf16(a2, bf[ks], C2, 0, 0, 0);
    C3 = __builtin_amdgcn_mfma_f32_16x16x32_bf16(a3, bf[ks], C3, 0, 0, 0);
  }
  const float bv = bias[n0 + w * 16 + ln];
  const size_t ncol = n0 + w * 16 + ln;
#pragma unroll
  for (int rt = 0; rt < 4; ++rt) {
    f32x4 Cf = (rt == 0) ? C0 : (rt == 1) ? C1 : (rt == 2) ? C2 : C3;
#pragma unroll
    for (int q = 0; q < 4; ++q) {
      float v = Cf[q] + bv;
      size_t idx = (size_t)(m0 + rt * 16 + cc * 4 + q) * N + ncol;
      if (OUTBF) ((ushort*)Cp)[idx] = (ushort)f2bf(v);
      else ((float*)Cp)[idx] = v;
    }
  }
}

// ---------------- Phase C: MFMA GRU. 16 blocks x 4 REAL batches, 512 threads.
// R13: HPITCH=144 (pitch_dw=72 == 8 mod 32): within each ds_read_b128 the 16
// (bl,c) lane-combos alias banks exactly 2-way (free) vs 4-way at pitch 136.
// MFMA source order chain-aware: ar/an interleaved first (feed r then a),
// az last (z only gates the final fma).
__global__ __attribute__((amdgpu_flat_work_group_size(512, 512)))
__attribute__((amdgpu_waves_per_eu(2, 2))) void gru_kernel(
    const ushort* __restrict__ Xp, const float* __restrict__ W_hh,
    const float* __restrict__ b_hh, float* __restrict__ rnn_out) {
  const int tid = threadIdx.x;
  const int w = tid >> 6;          // wave 0..7 -> h-dims [w*16, w*16+16)
  const int lane = tid & 63;
  const int ln = lane & 15;        // W row within tile; batch col = ln&3
  const int c = lane >> 4;         // k-group & row-quad 0..3
  const int bl = ln & 3;           // this lane's batch (0..3)
  const int qs = ln >> 2;          // this lane's C-reg / row-within-quad
  const int b0 = blockIdx.x * 4;   // four batches per block

  __shared__ alignas(16) short hlds[2][4 * HPITCH];  // bf16 h, dbuf x 4 batches

  bf16x8 wf[3][4];
#pragma unroll
  for (int gt = 0; gt < 3; ++gt) {
    const float* wr = W_hh + (size_t)(gt * 128 + w * 16 + ln) * 128 + c * 8;
#pragma unroll
    for (int ks = 0; ks < 4; ++ks) {
      bf16x8 f;
#pragma unroll
      for (int j = 0; j < 8; ++j) f[j] = f2bf(wr[ks * 32 + j]);
      wf[gt][ks] = f;
    }
  }
  const f32x4 br = *(const f32x4*)(b_hh + w * 16 + c * 4);
  const f32x4 bz = *(const f32x4*)(b_hh + 128 + w * 16 + c * 4);
  const f32x4 bn = *(const f32x4*)(b_hh + 256 + w * 16 + c * 4);

  // zero both h buffers (2*4*144 shorts = 576 dwords)
  for (int i = tid; i < 576; i += 512) ((uint32_t*)hlds)[i] = 0;

  const int dim = w * 16 + c * 4 + qs;         // this lane's h-dim
  const ushort* xs = Xp + (size_t)(b0 + bl) * SS * G3 + dim;
  float* rsp = rnn_out + (size_t)(b0 + bl) * SS * Hn + dim;

  // depth-2 prefetch state: set0 feeds even steps, set1 odd steps
  ushort xr0 = xs[0], xz0 = xs[128], xn0 = xs[256];
  ushort xr1 = xs[G3 + 0], xz1 = xs[G3 + 128], xn1 = xs[G3 + 256];
  const ushort* xpf = xs + 2 * (size_t)G3;     // prefetch cursor (t+2)

  float h_old = 0.0f;
  LDS_BARRIER();

  // one GRU half-step: reads hlds[RB], publishes hlds[RB^1].
  // xr/xz/xn consumed then refilled from xpf (branch-free overrun into
  // allocated scratch past Xp on the final iterations -- values unread).
#define GRU_STEP(RB, XR, XZ, XN)                                             \
  {                                                                          \
    const short* hr = hlds[RB] + bl * HPITCH;                                \
    bf16x8 h0 = *(const bf16x8*)(hr + 0 * 32 + c * 8);                       \
    bf16x8 h1 = *(const bf16x8*)(hr + 1 * 32 + c * 8);                       \
    bf16x8 h2 = *(const bf16x8*)(hr + 2 * 32 + c * 8);                       \
    bf16x8 h3 = *(const bf16x8*)(hr + 3 * 32 + c * 8);                       \
    ushort pr = xpf[0], pz = xpf[128], pn = xpf[256];                        \
    xpf += G3;                                                               \
    __builtin_amdgcn_s_setprio(1);                                           \
    f32x4 ar = br, az = bz, an = bn;                                         \
    ar = __builtin_amdgcn_mfma_f32_16x16x32_bf16(wf[0][0], h0, ar, 0, 0, 0); \
    an = __builtin_amdgcn_mfma_f32_16x16x32_bf16(wf[2][0], h0, an, 0, 0, 0); \
    ar = __builtin_amdgcn_mfma_f32_16x16x32_bf16(wf[0][1], h1, ar, 0, 0, 0); \
    an = __builtin_amdgcn_mfma_f32_16x16x32_bf16(wf[2][1], h1, an, 0, 0, 0); \
    ar = __builtin_amdgcn_mfma_f32_16x16x32_bf16(wf[0][2], h2, ar, 0, 0, 0); \
    an = __builtin_amdgcn_mfma_f32_16x16x32_bf16(wf[2][2], h2, an, 0, 0, 0); \
    ar = __builtin_amdgcn_mfma_f32_16x16x32_bf16(wf[0][3], h3, ar, 0, 0, 0); \
    an = __builtin_amdgcn_mfma_f32_16x16x32_bf16(wf[2][3], h3, an, 0, 0, 0); \
    az = __builtin_amdgcn_mfma_f32_16x16x32_bf16(wf[1][0], h0, az, 0, 0, 0); \
    az = __builtin_amdgcn_mfma_f32_16x16x32_bf16(wf[1][1], h1, az, 0, 0, 0); \
    az = __builtin_amdgcn_mfma_f32_16x16x32_bf16(wf[1][2], h2, az, 0, 0, 0); \
    az = __builtin_amdgcn_mfma_f32_16x16x32_bf16(wf[1][3], h3, az, 0, 0, 0); \
    __builtin_amdgcn_s_setprio(0);                                           \
    float ga = sel4(ar, qs), gz = sel4(az, qs), gn = sel4(an, qs);           \
    float r = sigmoid_f(bf2f(XR) + ga);                                      \
    float a = bf2f(XN) + r * gn;                                             \
    float e = __expf(-2.0f * a);                                             \
    float n = 2.0f * __builtin_amdgcn_rcpf(1.0f + e) - 1.0f;                 \
    float z = sigmoid_f(bf2f(XZ) + gz);                                      \
    float hn = n + z * (h_old - n);                                          \
    h_old = hn;                                                              \
    hlds[RB ^ 1][bl * HPITCH + dim] = f2bf(hn);                              \
    LDS_BARRIER();                                                           \
    *rsp = hn;                                                               \
    rsp += Hn;                                                               \
    XR = pr; XZ = pz; XN = pn;                                               \
  }

  for (int t = 0; t < SS; t += 2) {
    GRU_STEP(0, xr0, xz0, xn0)
    GRU_STEP(1, xr1, xz1, xn1)
  }
#undef GRU_STEP
}

// ---------------- Phase D2: s[pos] = sum_a tanh(tmpA[pos,a]) * sim_w[a]
__global__ __launch_bounds__(256) void score_kernel(
    const float* __restrict__ tmpA, const float* __restrict__ sim_w,
    float* __restrict__ s) {
  int pos = blockIdx.x * 4 + (threadIdx.x >> 6);
  int lane = threadIdx.x & 63;
  const float* row = tmpA + (size_t)pos * 128;
  float v = tanh_f(row[lane]) * sim_w[lane] +
            tanh_f(row[lane + 64]) * sim_w[lane + 64];
#pragma unroll
  for (int o = 32; o; o >>= 1) v += __shfl_down(v, o);
  if (lane == 0) s[pos] = v;
}

// ---------------- Phase E: cumulative softmax-average + exclusive cumsum.
// 128 blocks (b x h-half) x 64 threads.
__global__ __launch_bounds__(64) void attn_kernel(
    const float* __restrict__ s, const float* __restrict__ rnn,
    float* __restrict__ excl) {
  const int b = blockIdx.x >> 1;
  const int h = ((blockIdx.x & 1) << 6) + threadIdx.x;
  const int tl = threadIdx.x;     // 0..63
  __shared__ float elds[SS];
  const float* sb = s + (size_t)b * SS;
  float m = -1e30f;
  for (int i = tl; i < SS; i += 64) m = fmaxf(m, sb[i]);
#pragma unroll
  for (int o = 32; o; o >>= 1) m = fmaxf(m, __shfl_xor(m, o));
  for (int i = tl; i < SS; i += 64) elds[i] = __expf(sb[i] - m);
  __syncthreads();

  const float* rb = rnn + (size_t)b * SS * Hn + h;
  float* eb = excl + (size_t)b * SS * Hn + h;
  float num = 0.f, den = 0.f, run = 0.f;
  float rcur = rb[0];
  for (int t = 0; t < SS; ++t) {
    float rnxt = (t < SS - 1) ? rb[(size_t)(t + 1) * Hn] : 0.0f;
    float e = elds[t];
    den += e;
    num += e * rcur;
    eb[(size_t)t * Hn] = run;                        // exclusive
    run += num * __builtin_amdgcn_rcpf(den);         // attn_t
    rcur = rnxt;
  }
}

// ---------------- Phase F: logits -> sigmoid. One wave per (b, t).
__global__ __launch_bounds__(256) void out_kernel(
    const float* __restrict__ excl, const float* __restrict__ rnn,
    const float* __restrict__ concept, const float* __restrict__ pred_w,
    const float* __restrict__ pred_b, float* __restrict__ out) {
  int idx = blockIdx.x * 4 + (threadIdx.x >> 6);    // [0, 64*1023)
  int lane = threadIdx.x & 63;
  if (idx >= BB * (SS - 1)) return;
  int b = idx / (SS - 1), t = idx % (SS - 1);
  const float* e = excl + ((size_t)b * SS + t) * Hn;
  const float* r = rnn + ((size_t)b * SS + t) * Hn;
  const float* c = concept + ((size_t)b * SS + t + 1) * DCn;
  float v = e[lane] * pred_w[lane] + e[lane + 64] * pred_w[lane + 64] +
            r[lane] * pred_w[128 + lane] + r[lane + 64] * pred_w[192 + lane] +
            c[lane] * pred_w[256 + lane];
#pragma unroll
  for (int o = 32; o; o >>= 1) v += __shfl_down(v, o);
  if (lane == 0) out[idx] = sigmoid_f(v + pred_b[0]);
}

extern "C" void kernel_launch(void* const* d_in, const int* in_sizes, int n_in,
                              void* d_out, int out_size, void* d_ws, size_t ws_size,
                              hipStream_t stream) {
  const int* qseq = (const int*)d_in[0];
  const int* cseq = (const int*)d_in[1];
  const int* q2c = (const int*)d_in[2];
  const int* q2cm = (const int*)d_in[3];
  const float* cemb = (const float*)d_in[4];
  const float* remb = (const float*)d_in[5];
  const float* mlp_w = (const float*)d_in[6];
  const float* mlp_b = (const float*)d_in[7];
  const float* sim_w = (const float*)d_in[8];
  const float* W_ih = (const float*)d_in[9];
  const float* b_ih = (const float*)d_in[10];
  const float* W_hh = (const float*)d_in[11];
  const float* b_hh = (const float*)d_in[12];
  const float* pred_w = (const float*)d_in[13];
  const float* pred_b = (const float*)d_in[14];
  float* out = (float*)d_out;

  // workspace layout (f32 element offsets)
  float* ws = (float*)d_ws;
  float* concept = ws;                       // [B,S,64]  f32   [0, 4194304)
  ushort* interb = (ushort*)(ws + 4194304);  // [B,S,128] bf16  [4194304, 8388608)
  ushort* Xp = (ushort*)(ws + 8388608);      // [B,S,384] bf16  [8388608, 20971520)
  float* rnn = ws + 20971520;                // [B,S,128] f32   [20971520, 29360128)
  ushort* Wihb = (ushort*)(ws + 29360128);   // 49152 bf16      [29360128, +24576)
  ushort* mlpwb = (ushort*)(ws + 29384704);  // 16384 bf16      [29384704, +8192)
  float* tmpA = ws + 29392896;               // [B,S,128] f32   [29392896, 37781504)
  float* sbuf = ws + 4194304;                // alias: inter dead after B1
  float* excl = ws + 8388608;                // alias: Xp dead after gru

  convw_kernel<<<256, 256, 0, stream>>>(W_ih, mlp_w, Wihb, mlpwb);
  embed_kernel<<<32768, 256, 0, stream>>>(qseq, cseq, q2c, q2cm, cemb, remb,
                                          interb, concept);
  gemm_mfma_kernel<false, true><<<dim3(1024, 6), 256, 0, stream>>>(
      interb, Wihb, b_ih, Xp, 384);
  gru_kernel<<<16, 512, 0, stream>>>(Xp, W_hh, b_hh, rnn);
  gemm_mfma_kernel<true, false><<<dim3(1024, 2), 256, 0, stream>>>(
      rnn, mlpwb, mlp_b, tmpA, 128);
  score_kernel<<<16384, 256, 0, stream>>>(tmpA, sim_w, sbuf);
  attn_kernel<<<128, 64, 0, stream>>>(sbuf, rnn, excl);
  out_kernel<<<16368, 256, 0, stream>>>(excl, rnn, concept, pred_w, pred_b, out);
}

// Round 15
// 509.393 us; speedup vs baseline: 2.8565x; 1.1244x over previous
//
#include <hip/hip_runtime.h>
#include <hip/hip_bf16.h>
#include <cstdint>

// Problem constants
#define BB 64
#define SS 1024
#define DCn 64
#define Hn 128
#define G3 384
#define HPITCH 144   // shorts per h-row: pitch_dw=72 == 8 mod 32 -> <=2-way banks (free)

using f32x4 = __attribute__((ext_vector_type(4))) float;
using bf16x8 = __attribute__((ext_vector_type(8))) short;

// rcp-based sigmoid: avoids IEEE div sequence per call
__device__ __forceinline__ float sigmoid_f(float x) {
  return __builtin_amdgcn_rcpf(1.0f + __expf(-x));
}
__device__ __forceinline__ float tanh_f(float x) {
  float xc = fminf(fmaxf(x, -15.0f), 15.0f);
  float t = __expf(-2.0f * xc);
  return (1.0f - t) * __builtin_amdgcn_rcpf(1.0f + t);
}
__device__ __forceinline__ short f2bf(float x) {
  union { float f; uint32_t u; } v; v.f = x;
  uint32_t r = v.u + 0x7FFFu + ((v.u >> 16) & 1u);   // RNE
  return (short)(r >> 16);
}
__device__ __forceinline__ float bf2f(ushort u) {
  union { uint32_t i; float f; } v; v.i = (uint32_t)u << 16; return v.f;
}
__device__ __forceinline__ float sel4(f32x4 v, int q) {
  float t0 = (q & 1) ? v[1] : v[0];
  float t1 = (q & 1) ? v[3] : v[2];
  return (q & 2) ? t1 : t0;
}

#define LDS_BARRIER() do {                                   \
    asm volatile("s_waitcnt lgkmcnt(0)" ::: "memory");       \
    __builtin_amdgcn_s_barrier();                            \
    __builtin_amdgcn_sched_barrier(0);                       \
  } while (0)

// ---------------- weight conversion: W_ih -> bf16; Baug[144][128] =
// [mlp_w(128) ; pred_w[0:128] ; pred_w[128:256] ; zeros(14)]
__global__ __launch_bounds__(256) void convw_kernel(
    const float* __restrict__ W_ih, const float* __restrict__ mlp_w,
    const float* __restrict__ pred_w,
    ushort* __restrict__ Wihb, ushort* __restrict__ Baug) {
  int i = blockIdx.x * 256 + threadIdx.x;      // [0, 67584)
  if (i < 49152) { Wihb[i] = (ushort)f2bf(W_ih[i]); return; }
  int j = i - 49152;                           // [0, 18432)
  int r = j >> 7, k = j & 127;
  float v = (r < 128) ? mlp_w[j]
          : (r == 128) ? pred_w[k]
          : (r == 129) ? pred_w[128 + k] : 0.0f;
  Baug[j] = (ushort)f2bf(v);
}

// ---------------- Phase A: embeddings + concat -> interb(bf16); C3[pos] =
// concept(pos,:) . pred_w[256:320] reduced in-wave (concept never stored).
__global__ __launch_bounds__(256) void embed_kernel(
    const int* __restrict__ qseq, const int* __restrict__ cseq,
    const int* __restrict__ q2c, const int* __restrict__ q2cm,
    const float* __restrict__ cemb, const float* __restrict__ remb,
    const float* __restrict__ pred_w,
    ushort* __restrict__ interb, float* __restrict__ C3) {
  int pos = blockIdx.x * 2 + (threadIdx.x >> 7);   // [0, 65536)
  int d = threadIdx.x & 127;
  int q = qseq[pos];
  int corr = cseq[pos];
  float val;
  if (d < 64) {
    float acc = 0.f, msum = 0.f;
#pragma unroll
    for (int c = 0; c < 4; ++c) {
      int id = q2c[q * 4 + c];
      float m = (float)q2cm[q * 4 + c];
      acc += m * cemb[id * 64 + d];
      msum += m;
    }
    val = acc / fmaxf(msum, 1.0f);
    // C3 reduction: waves 0/2 hold pos's concept dims 0..63 in lanes 0..63
    float p3 = val * pred_w[256 + d];
#pragma unroll
    for (int o = 32; o; o >>= 1) p3 += __shfl_down(p3, o);
    if (d == 0) C3[pos] = p3;
  } else {
    val = remb[corr * 64 + (d - 64)];
  }
  int slot = (corr == 1) ? d : ((d < 64) ? d + 64 : d - 64);
  interb[(size_t)pos * 128 + slot] = (ushort)f2bf(val);
}

// ---------------- MFMA GEMM (B1): C[M,N] = A[M,128]*Bm[N,128]^T + bias, bf16 out
__global__ __launch_bounds__(256) void gemm_mfma_kernel(
    const ushort* __restrict__ Ap, const ushort* __restrict__ Bp,
    const float* __restrict__ bias, ushort* __restrict__ Cp, int N) {
  __shared__ bf16x8 Al[64][16];
  __shared__ bf16x8 Bl[64][16];
  const int m0 = blockIdx.x * 64, n0 = blockIdx.y * 64;
  const int tid = threadIdx.x;
  const int row = tid >> 2, j0 = (tid & 3) * 4;
  {
    const bf16x8* A = (const bf16x8*)Ap + (size_t)(m0 + row) * 16 + j0;
#pragma unroll
    for (int jj = 0; jj < 4; ++jj) Al[row][(j0 + jj) ^ (row & 15)] = A[jj];
    const bf16x8* Bg = (const bf16x8*)Bp + (size_t)(n0 + row) * 16 + j0;
#pragma unroll
    for (int jj = 0; jj < 4; ++jj) Bl[row][(j0 + jj) ^ (row & 15)] = Bg[jj];
  }
  __syncthreads();
  const int w = tid >> 6, lane = tid & 63, ln = lane & 15, cc = lane >> 4;
  bf16x8 bfr[4];
#pragma unroll
  for (int ks = 0; ks < 4; ++ks) bfr[ks] = Bl[w * 16 + ln][(ks * 4 + cc) ^ ln];
  f32x4 C0 = {0,0,0,0}, C1 = {0,0,0,0}, C2 = {0,0,0,0}, C3v = {0,0,0,0};
#pragma unroll
  for (int ks = 0; ks < 4; ++ks) {
    bf16x8 a0 = Al[0 * 16 + ln][(ks * 4 + cc) ^ ln];
    bf16x8 a1 = Al[1 * 16 + ln][(ks * 4 + cc) ^ ln];
    bf16x8 a2 = Al[2 * 16 + ln][(ks * 4 + cc) ^ ln];
    bf16x8 a3 = Al[3 * 16 + ln][(ks * 4 + cc) ^ ln];
    C0 = __builtin_amdgcn_mfma_f32_16x16x32_bf16(a0, bfr[ks], C0, 0, 0, 0);
    C1 = __builtin_amdgcn_mfma_f32_16x16x32_bf16(a1, bfr[ks], C1, 0, 0, 0);
    C2 = __builtin_amdgcn_mfma_f32_16x16x32_bf16(a2, bfr[ks], C2, 0, 0, 0);
    C3v = __builtin_amdgcn_mfma_f32_16x16x32_bf16(a3, bfr[ks], C3v, 0, 0, 0);
  }
  const float bv = bias[n0 + w * 16 + ln];
  const size_t ncol = n0 + w * 16 + ln;
#pragma unroll
  for (int rt = 0; rt < 4; ++rt) {
    f32x4 Cf = (rt == 0) ? C0 : (rt == 1) ? C1 : (rt == 2) ? C2 : C3v;
#pragma unroll
    for (int q = 0; q < 4; ++q)
      Cp[(size_t)(m0 + rt * 16 + cc * 4 + q) * N + ncol] = (ushort)f2bf(Cf[q] + bv);
  }
}

// ---------------- Phase C: MFMA GRU (structure verified R6-R13, unchanged)
__global__ __attribute__((amdgpu_flat_work_group_size(512, 512)))
__attribute__((amdgpu_waves_per_eu(2, 2))) void gru_kernel(
    const ushort* __restrict__ Xp, const float* __restrict__ W_hh,
    const float* __restrict__ b_hh, float* __restrict__ rnn_out) {
  const int tid = threadIdx.x;
  const int w = tid >> 6;
  const int lane = tid & 63;
  const int ln = lane & 15;
  const int c = lane >> 4;
  const int bl = ln & 3;
  const int qs = ln >> 2;
  const int b0 = blockIdx.x * 4;

  __shared__ alignas(16) short hlds[2][4 * HPITCH];

  bf16x8 wf[3][4];
#pragma unroll
  for (int gt = 0; gt < 3; ++gt) {
    const float* wr = W_hh + (size_t)(gt * 128 + w * 16 + ln) * 128 + c * 8;
#pragma unroll
    for (int ks = 0; ks < 4; ++ks) {
      bf16x8 f;
#pragma unroll
      for (int j = 0; j < 8; ++j) f[j] = f2bf(wr[ks * 32 + j]);
      wf[gt][ks] = f;
    }
  }
  const f32x4 br = *(const f32x4*)(b_hh + w * 16 + c * 4);
  const f32x4 bz = *(const f32x4*)(b_hh + 128 + w * 16 + c * 4);
  const f32x4 bn = *(const f32x4*)(b_hh + 256 + w * 16 + c * 4);

  for (int i = tid; i < 576; i += 512) ((uint32_t*)hlds)[i] = 0;

  const int dim = w * 16 + c * 4 + qs;
  const ushort* xs = Xp + (size_t)(b0 + bl) * SS * G3 + dim;
  float* rsp = rnn_out + (size_t)(b0 + bl) * SS * Hn + dim;

  ushort xr0 = xs[0], xz0 = xs[128], xn0 = xs[256];
  ushort xr1 = xs[G3 + 0], xz1 = xs[G3 + 128], xn1 = xs[G3 + 256];
  const ushort* xpf = xs + 2 * (size_t)G3;

  float h_old = 0.0f;
  LDS_BARRIER();

#define GRU_STEP(RB, XR, XZ, XN)                                             \
  {                                                                          \
    const short* hr = hlds[RB] + bl * HPITCH;                                \
    bf16x8 h0 = *(const bf16x8*)(hr + 0 * 32 + c * 8);                       \
    bf16x8 h1 = *(const bf16x8*)(hr + 1 * 32 + c * 8);                       \
    bf16x8 h2 = *(const bf16x8*)(hr + 2 * 32 + c * 8);                       \
    bf16x8 h3 = *(const bf16x8*)(hr + 3 * 32 + c * 8);                       \
    ushort pr = xpf[0], pz = xpf[128], pn = xpf[256];                        \
    xpf += G3;                                                               \
    __builtin_amdgcn_s_setprio(1);                                           \
    f32x4 ar = br, az = bz, an = bn;                                         \
    ar = __builtin_amdgcn_mfma_f32_16x16x32_bf16(wf[0][0], h0, ar, 0, 0, 0); \
    an = __builtin_amdgcn_mfma_f32_16x16x32_bf16(wf[2][0], h0, an, 0, 0, 0); \
    ar = __builtin_amdgcn_mfma_f32_16x16x32_bf16(wf[0][1], h1, ar, 0, 0, 0); \
    an = __builtin_amdgcn_mfma_f32_16x16x32_bf16(wf[2][1], h1, an, 0, 0, 0); \
    ar = __builtin_amdgcn_mfma_f32_16x16x32_bf16(wf[0][2], h2, ar, 0, 0, 0); \
    an = __builtin_amdgcn_mfma_f32_16x16x32_bf16(wf[2][2], h2, an, 0, 0, 0); \
    ar = __builtin_amdgcn_mfma_f32_16x16x32_bf16(wf[0][3], h3, ar, 0, 0, 0); \
    an = __builtin_amdgcn_mfma_f32_16x16x32_bf16(wf[2][3], h3, an, 0, 0, 0); \
    az = __builtin_amdgcn_mfma_f32_16x16x32_bf16(wf[1][0], h0, az, 0, 0, 0); \
    az = __builtin_amdgcn_mfma_f32_16x16x32_bf16(wf[1][1], h1, az, 0, 0, 0); \
    az = __builtin_amdgcn_mfma_f32_16x16x32_bf16(wf[1][2], h2, az, 0, 0, 0); \
    az = __builtin_amdgcn_mfma_f32_16x16x32_bf16(wf[1][3], h3, az, 0, 0, 0); \
    __builtin_amdgcn_s_setprio(0);                                           \
    float ga = sel4(ar, qs), gz = sel4(az, qs), gn = sel4(an, qs);           \
    float r = sigmoid_f(bf2f(XR) + ga);                                      \
    float a = bf2f(XN) + r * gn;                                             \
    float e = __expf(-2.0f * a);                                             \
    float n = 2.0f * __builtin_amdgcn_rcpf(1.0f + e) - 1.0f;                 \
    float z = sigmoid_f(bf2f(XZ) + gz);                                      \
    float hn = n + z * (h_old - n);                                          \
    h_old = hn;                                                              \
    hlds[RB ^ 1][bl * HPITCH + dim] = f2bf(hn);                              \
    LDS_BARRIER();                                                           \
    *rsp = hn;                                                               \
    rsp += Hn;                                                               \
    XR = pr; XZ = pz; XN = pn;                                               \
  }

  for (int t = 0; t < SS; t += 2) {
    GRU_STEP(0, xr0, xz0, xn0)
    GRU_STEP(1, xr1, xz1, xn1)
  }
#undef GRU_STEP
}

// ---------------- Fused A2 GEMM + score + D-dots. Grid 1024 blocks, 256 thr.
// Baug[144][128]: cols 0..127 -> tanh()*sim_w row-reduced into s;
// col 128 -> D1 = rnn.pred_w[0:128]; col 129 -> D2 = rnn.pred_w[128:256].
__global__ __launch_bounds__(256) void gemm_score_kernel(
    const float* __restrict__ rnn, const ushort* __restrict__ Baug,
    const float* __restrict__ mlp_b, const float* __restrict__ sim_w,
    float* __restrict__ s, float* __restrict__ D1, float* __restrict__ D2) {
  __shared__ bf16x8 Al[64][16];
  __shared__ bf16x8 Bl[144][16];
  __shared__ float srow[64][4];
  const int m0 = blockIdx.x * 64;
  const int tid = threadIdx.x;
  {
    const int row = tid >> 2, j0 = (tid & 3) * 4;
    const float* A = rnn + (size_t)(m0 + row) * 128 + j0 * 8;
#pragma unroll
    for (int jj = 0; jj < 4; ++jj) {
      f32x4 lo = *(const f32x4*)(A + jj * 8);
      f32x4 hi = *(const f32x4*)(A + jj * 8 + 4);
      bf16x8 v;
#pragma unroll
      for (int q = 0; q < 4; ++q) { v[q] = f2bf(lo[q]); v[4 + q] = f2bf(hi[q]); }
      Al[row][(j0 + jj) ^ (row & 15)] = v;
    }
  }
  {
    const bf16x8* Bg = (const bf16x8*)Baug;
    for (int i = tid; i < 144 * 16; i += 256) {
      int r = i >> 4, j = i & 15;
      Bl[r][j ^ (r & 15)] = Bg[i];
    }
  }
  __syncthreads();
  const int w = tid >> 6, lane = tid & 63, ln = lane & 15, cc = lane >> 4;
  float racc[4][4] = {};
  for (int nt = w; nt < 9; nt += 4) {
    bf16x8 bfr[4];
#pragma unroll
    for (int ks = 0; ks < 4; ++ks) bfr[ks] = Bl[nt * 16 + ln][(ks * 4 + cc) ^ ln];
    f32x4 C0 = {0,0,0,0}, C1 = {0,0,0,0}, C2 = {0,0,0,0}, C3v = {0,0,0,0};
#pragma unroll
    for (int ks = 0; ks < 4; ++ks) {
      bf16x8 a0 = Al[0 * 16 + ln][(ks * 4 + cc) ^ ln];
      bf16x8 a1 = Al[1 * 16 + ln][(ks * 4 + cc) ^ ln];
      bf16x8 a2 = Al[2 * 16 + ln][(ks * 4 + cc) ^ ln];
      bf16x8 a3 = Al[3 * 16 + ln][(ks * 4 + cc) ^ ln];
      C0 = __builtin_amdgcn_mfma_f32_16x16x32_bf16(a0, bfr[ks], C0, 0, 0, 0);
      C1 = __builtin_amdgcn_mfma_f32_16x16x32_bf16(a1, bfr[ks], C1, 0, 0, 0);
      C2 = __builtin_amdgcn_mfma_f32_16x16x32_bf16(a2, bfr[ks], C2, 0, 0, 0);
      C3v = __builtin_amdgcn_mfma_f32_16x16x32_bf16(a3, bfr[ks], C3v, 0, 0, 0);
    }
    if (nt < 8) {
      const int col = nt * 16 + ln;
      const float bv = mlp_b[col];
      const float sw = sim_w[col];
#pragma unroll
      for (int rt = 0; rt < 4; ++rt) {
        f32x4 Cf = (rt == 0) ? C0 : (rt == 1) ? C1 : (rt == 2) ? C2 : C3v;
#pragma unroll
        for (int q = 0; q < 4; ++q)
          racc[rt][q] += tanh_f(Cf[q] + bv) * sw;
      }
    } else if (ln < 2) {
      float* Dp = (ln == 0) ? D1 : D2;
#pragma unroll
      for (int rt = 0; rt < 4; ++rt) {
        f32x4 Cf = (rt == 0) ? C0 : (rt == 1) ? C1 : (rt == 2) ? C2 : C3v;
#pragma unroll
        for (int q = 0; q < 4; ++q)
          Dp[m0 + rt * 16 + cc * 4 + q] = Cf[q];
      }
    }
  }
  // reduce score partials over the 16 ln lanes (cols) within each wave
#pragma unroll
  for (int o = 1; o <= 8; o <<= 1)
#pragma unroll
    for (int rt = 0; rt < 4; ++rt)
#pragma unroll
      for (int q = 0; q < 4; ++q)
        racc[rt][q] += __shfl_xor(racc[rt][q], o);
  if (ln == 0)
#pragma unroll
    for (int rt = 0; rt < 4; ++rt)
#pragma unroll
      for (int q = 0; q < 4; ++q)
        srow[rt * 16 + cc * 4 + q][w] = racc[rt][q];
  __syncthreads();
  if (tid < 64)
    s[m0 + tid] = srow[tid][0] + srow[tid][1] + srow[tid][2] + srow[tid][3];
}

// ---------------- Fused attention + output. Scalarized recurrence:
// excl(t).pw1 = P_run with P_num += e_t*D1_t ; P_run += P_num/den_t.
// den via parallel prefix scan. out[b,t] = sigmoid(P_run + D2_t + C3_{t+1} + pb).
__global__ __launch_bounds__(128) void attn_final_kernel(
    const float* __restrict__ s, const float* __restrict__ D1,
    const float* __restrict__ D2, const float* __restrict__ C3,
    const float* __restrict__ pred_b, float* __restrict__ out) {
  const int b = blockIdx.x;
  const int tid = threadIdx.x;   // 128
  __shared__ float elds[SS];
  __shared__ float rcpd[SS];
  __shared__ float d1l[SS];
  __shared__ float dcl[SS];
  __shared__ float red[2];
  __shared__ float wtot[2];
  const float pb = pred_b[0];
  const float* sb = s + (size_t)b * SS;
  const float* d1b = D1 + (size_t)b * SS;
  const float* d2b = D2 + (size_t)b * SS;
  const float* c3b = C3 + (size_t)b * SS;
  float m = -1e30f;
  for (int i = tid; i < SS; i += 128) m = fmaxf(m, sb[i]);
#pragma unroll
  for (int o = 32; o; o >>= 1) m = fmaxf(m, __shfl_xor(m, o));
  if ((tid & 63) == 0) red[tid >> 6] = m;
  __syncthreads();
  m = fmaxf(red[0], red[1]);
  for (int i = tid; i < SS; i += 128) {
    elds[i] = __expf(sb[i] - m);
    d1l[i] = d1b[i];
    dcl[i] = d2b[i] + ((i < SS - 1) ? c3b[i + 1] : 0.0f) + pb;
  }
  __syncthreads();
  // inclusive prefix scan of e -> den; rcpd = 1/den
  {
    const int base = tid * 8;
    float v[8];
    float run = 0.f;
#pragma unroll
    for (int k = 0; k < 8; ++k) { run += elds[base + k]; v[k] = run; }
    float tot = run, sc = tot;
#pragma unroll
    for (int o = 1; o < 64; o <<= 1) {
      float u = __shfl_up(sc, o);
      if ((tid & 63) >= o) sc += u;
    }
    if ((tid & 63) == 63) wtot[tid >> 6] = sc;
    __syncthreads();
    float excl = sc - tot;
    if (tid >= 64) excl += wtot[0];
#pragma unroll
    for (int k = 0; k < 8; ++k)
      rcpd[base + k] = __builtin_amdgcn_rcpf(v[k] + excl);
  }
  __syncthreads();
  // serial scalar recurrence (all lanes duplicate; lane 0 stores)
  float P_num = 0.f, P_run = 0.f;
  float* ob = out + (size_t)b * (SS - 1);
  for (int t = 0; t < SS; t += 4) {
    f32x4 e4 = *(const f32x4*)&elds[t];
    f32x4 r4 = *(const f32x4*)&rcpd[t];
    f32x4 d4 = *(const f32x4*)&d1l[t];
    f32x4 c4 = *(const f32x4*)&dcl[t];
#pragma unroll
    for (int k = 0; k < 4; ++k) {
      P_num += e4[k] * d4[k];
      float v = sigmoid_f(P_run + c4[k]);
      if (tid == 0 && (t + k) < SS - 1) ob[t + k] = v;
      P_run += P_num * r4[k];
    }
  }
}

extern "C" void kernel_launch(void* const* d_in, const int* in_sizes, int n_in,
                              void* d_out, int out_size, void* d_ws, size_t ws_size,
                              hipStream_t stream) {
  const int* qseq = (const int*)d_in[0];
  const int* cseq = (const int*)d_in[1];
  const int* q2c = (const int*)d_in[2];
  const int* q2cm = (const int*)d_in[3];
  const float* cemb = (const float*)d_in[4];
  const float* remb = (const float*)d_in[5];
  const float* mlp_w = (const float*)d_in[6];
  const float* mlp_b = (const float*)d_in[7];
  const float* sim_w = (const float*)d_in[8];
  const float* W_ih = (const float*)d_in[9];
  const float* b_ih = (const float*)d_in[10];
  const float* W_hh = (const float*)d_in[11];
  const float* b_hh = (const float*)d_in[12];
  const float* pred_w = (const float*)d_in[13];
  const float* pred_b = (const float*)d_in[14];
  float* out = (float*)d_out;

  // workspace layout -- ALL offsets in f32 slots; bf16 regions converted
  // ushort->f32 explicitly (R14's bug: used ushort counts as f32 offsets).
  float* ws = (float*)d_ws;
  ushort* interb = (ushort*)ws;              // 8,388,608 us = [0, 4194304)
  ushort* Xp = (ushort*)(ws + 4194304);      // 25,165,824 us = [4194304, 16777216)
  float* rnn = ws + 16777216;                // 8,388,608 f32 = [16777216, 25165824)
  ushort* Wihb = (ushort*)(ws + 25165824);   // 49,152 us = 24,576 f32 -> [25165824, 25190400)
  ushort* Baug = (ushort*)(ws + 25190400);   // 18,432 us = 9,216 f32 -> [25190400, 25199616)
  float* sbuf = ws + 25199616;               // 65,536 f32 -> [25199616, 25265152)
  float* D1 = ws + 25265152;                 // 65,536 f32 -> [25265152, 25330688)
  float* D2 = ws + 25330688;                 // 65,536 f32 -> [25330688, 25396224)
  float* C3 = ws + 25396224;                 // 65,536 f32 -> [25396224, 25461760)

  convw_kernel<<<264, 256, 0, stream>>>(W_ih, mlp_w, pred_w, Wihb, Baug);
  embed_kernel<<<32768, 256, 0, stream>>>(qseq, cseq, q2c, q2cm, cemb, remb,
                                          pred_w, interb, C3);
  gemm_mfma_kernel<<<dim3(1024, 6), 256, 0, stream>>>(interb, Wihb, b_ih, Xp, 384);
  gru_kernel<<<16, 512, 0, stream>>>(Xp, W_hh, b_hh, rnn);
  gemm_score_kernel<<<1024, 256, 0, stream>>>(rnn, Baug, mlp_b, sim_w,
                                              sbuf, D1, D2);
  attn_final_kernel<<<64, 128, 0, stream>>>(sbuf, D1, D2, C3, pred_b, out);
}